// Round 1
// 390.524 us; speedup vs baseline: 1.1312x; 1.1312x over previous
//
#include <hip/hip_runtime.h>
#include <hip/hip_bf16.h>

// GraphSAGE (GCN-aggregator) — 3 layers, fp32.
// Structure: transform-then-aggregate ((seg(t)+t)*inv + b, t = h@W^T).
// R8 change: agg_t_k held the full W row per lane in 64 registers (wreg).
// gfx950's unified VGPR/AGPR file let the compiler park it in AGPRs —
// reported VGPR_Count=84 but true allocation ~184 -> 2 waves/SIMD ->
// OccupancyPercent 27%, latency-bound gathers. W now lives in LDS
// (padded stride 17 float4: lane l's b128 at dword 68l+4c hits the
// structural 8-slot bank minimum, conflict-free). launch_bounds(256,4)
// pins total regs <=128 -> 4 waves/SIMD. Epilogue o_acc split into two
// chains to halve the serial fma dependency.
// fp32 throughout (bf16 would exceed the 7.1e-4 absmax threshold).

#define N_FEAT 64
#define CAP 64    // ELL slots per node (4 planes of 16)
#define CAPW 24   // bin slots per (bucket, wave)
#define OVF_CAP 4096

__device__ __forceinline__ float rl(float v, int l) {
    return __int_as_float(__builtin_amdgcn_readlane(__float_as_int(v), l));
}

// ---- bin_edges body: bin edges by dst bucket (atomic-free, packed cnt) ----
__device__ __forceinline__ void bin_body(const int* __restrict__ src,
                                         const int* __restrict__ dst,
                                         unsigned int* __restrict__ bins,  // [8, nw, CAPW]
                                         unsigned long long* __restrict__ cnt64,  // [nw]
                                         int* __restrict__ ovf, int* __restrict__ ovf_cnt,
                                         int n_edges, int bsize, int nw, int bid) {
    const int e = bid * 256 + threadIdx.x;
    const int lane = threadIdx.x & 63;
    const int wid = (bid << 2) | (threadIdx.x >> 6);
    const bool valid = e < n_edges;
    int s = 0, d = 0;
    if (valid) { s = src[e]; d = dst[e]; }
    const unsigned int bucket = valid ? ((unsigned int)d / (unsigned int)bsize) : 8u;
    const unsigned int local = valid ? (unsigned int)(d - (int)bucket * bsize) : 0u;
    const unsigned int pack = (local << 17) | (unsigned int)s;

    int mycnt = 0;
    for (int c = 0; c < 8; ++c) {
        unsigned long long m = __ballot(valid && bucket == (unsigned int)c);
        int cc = __popcll(m);
        if (lane == c) mycnt = (cc < CAPW) ? cc : CAPW;
        if (valid && bucket == (unsigned int)c) {
            int pfx = __popcll(m & ((1ull << lane) - 1ull));
            if (pfx < CAPW) {
                __builtin_nontemporal_store(pack, &bins[((size_t)c * nw + wid) * CAPW + pfx]);
            } else {
                int p = atomicAdd(ovf_cnt, 1);
                if (p < OVF_CAP) { ovf[2 * p] = s; ovf[2 * p + 1] = d; }
            }
        }
    }
    unsigned long long packed = 0;
#pragma unroll
    for (int c = 0; c < 8; ++c) {
        int v = __builtin_amdgcn_readlane(mycnt, c);
        packed |= ((unsigned long long)(v & 0xFF)) << (8 * c);
    }
    if (lane == 0) cnt64[wid] = packed;
}

// ---- transform body: t[node][o] = sum_f h[node][f] * W[o][f]  (OUT=64) ----
__device__ __forceinline__ void transform64_body(const float* __restrict__ h,
                                                 const float* __restrict__ W,
                                                 float* __restrict__ t, int n_nodes, int bid) {
    const int lane = threadIdx.x & 63;
    const int wave = (bid << 2) | (threadIdx.x >> 6);
    float4 wreg[16];
    const float4* W4 = (const float4*)(W + lane * N_FEAT);
#pragma unroll
    for (int k = 0; k < 16; ++k) wreg[k] = W4[k];
    const float* wf = (const float*)wreg;

    const int node0 = wave * 8;
    for (int k = 0; k < 8; ++k) {
        const int node = node0 + k;
        if (node >= n_nodes) return;  // wave-uniform
        const float hv = h[(size_t)node * N_FEAT + lane];
        float acc = 0.f;
#pragma unroll
        for (int f = 0; f < 64; ++f) acc = fmaf(rl(hv, f), wf[f], acc);
        t[(size_t)node * N_FEAT + lane] = acc;
    }
}

// ---- fused: bin_edges (blocks [0,PB)) || transform0 (blocks [PB, PB+tb)) ----
__global__ __launch_bounds__(256) void prep(const int* __restrict__ src,
                                            const int* __restrict__ dst,
                                            unsigned int* __restrict__ bins,
                                            unsigned long long* __restrict__ cnt64,
                                            int* __restrict__ ovf, int* __restrict__ ovf_cnt,
                                            int n_edges, int bsize, int nw,
                                            const float* __restrict__ feats,
                                            const float* __restrict__ W0,
                                            float* __restrict__ t0, int n_nodes, int PB) {
    const int b = (int)blockIdx.x;
    if (b < PB)
        bin_body(src, dst, bins, cnt64, ovf, ovf_cnt, n_edges, bsize, nw, b);
    else
        transform64_body(feats, W0, t0, n_nodes, b - PB);
}

// ---- phase 2: scatter bins into plane-split ELL; bucket = blockIdx%8 ----
__global__ __launch_bounds__(256) void fill_from_bins(const unsigned int* __restrict__ bins,
                                                      const unsigned long long* __restrict__ cnt64,
                                                      const int* __restrict__ ovf,
                                                      const int* __restrict__ ovf_cnt,
                                                      int* __restrict__ deg,
                                                      int* __restrict__ ell,
                                                      int nw, int bsize, int n_nodes) {
    const int lane = threadIdx.x & 63;
    const int w = threadIdx.x >> 6;
    const int c = blockIdx.x & 7;          // bucket -> XCD (round-robin dispatch)
    const int jb = blockIdx.x >> 3;
    const int base_node = c * bsize;
    const int sub = lane >> 3;             // 8 sub-segments per wave
    const int rr = lane & 7;               // record id within tier
    const int wave_in_bucket = jb * 4 + w;
    const int nwaves = (gridDim.x >> 3) * 4;
    const int shift = 8 * c;

    for (int s0 = wave_in_bucket * 8; s0 < nw; s0 += nwaves * 8) {
        const int sg = s0 + sub;
        unsigned long long word = (sg < nw) ? cnt64[sg] : 0ull;  // one 64B line/iter
        const int n = (int)((word >> shift) & 0xFFull);
#pragma unroll
        for (int t = 0; t < 3; ++t) {          // tiers: records 0-7, 8-15, 16-23
            const int rec = t * 8 + rr;
            const bool act = rec < n;
            unsigned long long bm = __ballot(act);
            if (!bm) break;                    // wave-uniform early out
            if (act) {
                unsigned int v = __builtin_nontemporal_load(
                    &bins[((size_t)c * nw + sg) * CAPW + rec]);
                int sv = (int)(v & 0x1FFFFu);
                int d = base_node + (int)(v >> 17);
                int slot = atomicAdd(&deg[d], 1);
                if (slot < CAP)
                    ell[(((size_t)(slot >> 4) * n_nodes + d) << 4) + (slot & 15)] = sv;
            }
        }
    }
    if (blockIdx.x == 0) {  // drain (expected-empty) overflow list
        int n = *ovf_cnt; n = (n < OVF_CAP) ? n : OVF_CAP;
        for (int i = threadIdx.x; i < n; i += 256) {
            int sv = ovf[2 * i], d = ovf[2 * i + 1];
            int slot = atomicAdd(&deg[d], 1);
            if (slot < CAP)
                ell[(((size_t)(slot >> 4) * n_nodes + d) << 4) + (slot & 15)] = sv;
        }
    }
}

// ---- fused agg + next transform:
//   h = relu((seg(t)+t)*inv + b); t_next[node][o] = sum_f h[f]*Wn[o][f]
// t is 64-wide; ELL plane layout: slot s at ell[((s>>4)*N + d)*16 + (s&15)].
// W staged in LDS (pad: stride 17 float4 = 68 floats -> lane l's
// ds_read_b128 at dword 68l+4c is at the 8-slot structural bank minimum).
template <int OUTW, int NPW>
__global__ __launch_bounds__(256, 4) void agg_t_k(const float* __restrict__ t,
                                                  const float* __restrict__ bias,  // [64]
                                                  const float* __restrict__ Wn,    // [OUTW,64]
                                                  const int* __restrict__ deg,
                                                  const int* __restrict__ ell,
                                                  float* __restrict__ tn,          // [N,OUTW]
                                                  int n_nodes) {
    __shared__ float4 sW[64 * 17];  // 17.4 KB, rows padded +1 float4
    {
        const float4* Wg = (const float4*)Wn;
        for (int i = threadIdx.x; i < OUTW * 16; i += 256)
            sW[(i >> 4) * 17 + (i & 15)] = Wg[i];
    }
    __syncthreads();

    const int lane = threadIdx.x & 63;
    const int wave = (blockIdx.x << 2) | (threadIdx.x >> 6);
    const int g = lane >> 4;
    const int q = lane & 15;
    const float4* t4 = (const float4*)t;
    const int4* ell4 = (const int4*)ell;
    const float4 bq = ((const float4*)bias)[q];
    const int wrow = (OUTW == 64) ? lane : ((lane < OUTW) ? lane : 0);
    const float4* wrow4 = sW + wrow * 17;
    const bool has_out = (OUTW == 64) || (lane < OUTW);

    const int node0 = wave * NPW;
    if (node0 >= n_nodes) return;
    const int e0 = g * 4;

    if (node0 + NPW <= n_nodes) {
        int dg[NPW];
#pragma unroll
        for (int k = 0; k < NPW; ++k) dg[k] = deg[node0 + k];
        float4 self[NPW];
#pragma unroll
        for (int k = 0; k < NPW; ++k) self[k] = t4[(size_t)(node0 + k) * 16 + q];

        int4 idxb[2];
        float4 vb[2][4];
        idxb[0] = ell4[(size_t)node0 * 4 + g];  // plane 0
        {
            int4 ix = idxb[0]; const int d = dg[0];
            vb[0][0] = t4[(size_t)((e0 + 0 < d) ? ix.x : 0) * 16 + q];
            vb[0][1] = t4[(size_t)((e0 + 1 < d) ? ix.y : 0) * 16 + q];
            vb[0][2] = t4[(size_t)((e0 + 2 < d) ? ix.z : 0) * 16 + q];
            vb[0][3] = t4[(size_t)((e0 + 3 < d) ? ix.w : 0) * 16 + q];
        }
        if (NPW > 1) idxb[1] = ell4[(size_t)(node0 + 1) * 4 + g];

#pragma unroll
        for (int k = 0; k < NPW; ++k) {
            if (k + 1 < NPW) {  // issue gathers for node k+1
                int4 ix = idxb[(k + 1) & 1]; const int d = dg[k + 1];
                float4* v = vb[(k + 1) & 1];
                v[0] = t4[(size_t)((e0 + 0 < d) ? ix.x : 0) * 16 + q];
                v[1] = t4[(size_t)((e0 + 1 < d) ? ix.y : 0) * 16 + q];
                v[2] = t4[(size_t)((e0 + 2 < d) ? ix.z : 0) * 16 + q];
                v[3] = t4[(size_t)((e0 + 3 < d) ? ix.w : 0) * 16 + q];
            }
            if (k + 2 < NPW) idxb[k & 1] = ell4[(size_t)(node0 + k + 2) * 4 + g];

            const int node = node0 + k;
            const int d = dg[k];
            const float4* v = vb[k & 1];
            const float m0 = (e0 + 0 < d) ? 1.f : 0.f;
            const float m1 = (e0 + 1 < d) ? 1.f : 0.f;
            const float m2 = (e0 + 2 < d) ? 1.f : 0.f;
            const float m3 = (e0 + 3 < d) ? 1.f : 0.f;
            float4 acc;
            acc.x = m0 * v[0].x; acc.y = m0 * v[0].y; acc.z = m0 * v[0].z; acc.w = m0 * v[0].w;
            acc.x = fmaf(m1, v[1].x, acc.x); acc.y = fmaf(m1, v[1].y, acc.y);
            acc.z = fmaf(m1, v[1].z, acc.z); acc.w = fmaf(m1, v[1].w, acc.w);
            acc.x = fmaf(m2, v[2].x, acc.x); acc.y = fmaf(m2, v[2].y, acc.y);
            acc.z = fmaf(m2, v[2].z, acc.z); acc.w = fmaf(m2, v[2].w, acc.w);
            acc.x = fmaf(m3, v[3].x, acc.x); acc.y = fmaf(m3, v[3].y, acc.y);
            acc.z = fmaf(m3, v[3].z, acc.z); acc.w = fmaf(m3, v[3].w, acc.w);

            const int dcap = (d < CAP) ? d : CAP;
            for (int u = 1; u * 16 < dcap; ++u) {  // tail: planes 1..3 (deg > 16)
                int4 ix = ell4[((size_t)u * n_nodes + node) * 4 + g];
                const int eb = u * 16 + g * 4;
                int i0 = (eb + 0 < d) ? ix.x : 0;
                int i1 = (eb + 1 < d) ? ix.y : 0;
                int i2 = (eb + 2 < d) ? ix.z : 0;
                int i3 = (eb + 3 < d) ? ix.w : 0;
                float n0 = (eb + 0 < d) ? 1.f : 0.f;
                float n1 = (eb + 1 < d) ? 1.f : 0.f;
                float n2 = (eb + 2 < d) ? 1.f : 0.f;
                float n3 = (eb + 3 < d) ? 1.f : 0.f;
                float4 w0 = t4[(size_t)i0 * 16 + q];
                float4 w1 = t4[(size_t)i1 * 16 + q];
                float4 w2 = t4[(size_t)i2 * 16 + q];
                float4 w3 = t4[(size_t)i3 * 16 + q];
                acc.x = fmaf(n0, w0.x, acc.x); acc.y = fmaf(n0, w0.y, acc.y);
                acc.z = fmaf(n0, w0.z, acc.z); acc.w = fmaf(n0, w0.w, acc.w);
                acc.x = fmaf(n1, w1.x, acc.x); acc.y = fmaf(n1, w1.y, acc.y);
                acc.z = fmaf(n1, w1.z, acc.z); acc.w = fmaf(n1, w1.w, acc.w);
                acc.x = fmaf(n2, w2.x, acc.x); acc.y = fmaf(n2, w2.y, acc.y);
                acc.z = fmaf(n2, w2.z, acc.z); acc.w = fmaf(n2, w2.w, acc.w);
                acc.x = fmaf(n3, w3.x, acc.x); acc.y = fmaf(n3, w3.y, acc.y);
                acc.z = fmaf(n3, w3.z, acc.z); acc.w = fmaf(n3, w3.w, acc.w);
            }

            acc.x += __shfl_xor(acc.x, 16, 64); acc.y += __shfl_xor(acc.y, 16, 64);
            acc.z += __shfl_xor(acc.z, 16, 64); acc.w += __shfl_xor(acc.w, 16, 64);
            acc.x += __shfl_xor(acc.x, 32, 64); acc.y += __shfl_xor(acc.y, 32, 64);
            acc.z += __shfl_xor(acc.z, 32, 64); acc.w += __shfl_xor(acc.w, 32, 64);

            // h (relu'd, bias'd) — replicated in all 4 groups per lane
            const float invv = 1.0f / (float)(d + 1);
            float4 r;
            r.x = fmaxf((acc.x + self[k].x) * invv + bq.x, 0.f);
            r.y = fmaxf((acc.y + self[k].y) * invv + bq.y, 0.f);
            r.z = fmaxf((acc.z + self[k].z) * invv + bq.z, 0.f);
            r.w = fmaxf((acc.w + self[k].w) * invv + bq.w, 0.f);

            // t_next[o] = sum_f h[f] * Wn[o][f]; h[4c+j] = readlane(r[j], c)
            // W row from LDS; two accumulator chains halve serial fma latency
            float o0 = 0.f, o1 = 0.f;
#pragma unroll
            for (int c = 0; c < 16; c += 2) {
                float4 w0 = wrow4[c];
                float4 w1 = wrow4[c + 1];
                o0 = fmaf(rl(r.x, c), w0.x, o0);
                o0 = fmaf(rl(r.y, c), w0.y, o0);
                o0 = fmaf(rl(r.z, c), w0.z, o0);
                o0 = fmaf(rl(r.w, c), w0.w, o0);
                o1 = fmaf(rl(r.x, c + 1), w1.x, o1);
                o1 = fmaf(rl(r.y, c + 1), w1.y, o1);
                o1 = fmaf(rl(r.z, c + 1), w1.z, o1);
                o1 = fmaf(rl(r.w, c + 1), w1.w, o1);
            }
            if (has_out) tn[(size_t)node * OUTW + lane] = o0 + o1;
        }
    } else {
        // generic tail path (not taken for N=100000, NPW=4)
        for (int k = 0; k < NPW; ++k) {
            const int node = node0 + k;
            if (node >= n_nodes) return;
            const int d = deg[node];
            const int dcap = (d < CAP) ? d : CAP;
            float4 acc = make_float4(0.f, 0.f, 0.f, 0.f);
            for (int u = 0; u * 16 < dcap; ++u) {
                int4 ix = ell4[((size_t)u * n_nodes + node) * 4 + g];
                const int eb = u * 16 + g * 4;
                for (int j = 0; j < 4; ++j) {
                    int ii = (j == 0) ? ix.x : (j == 1) ? ix.y : (j == 2) ? ix.z : ix.w;
                    float mm = (eb + j < d) ? 1.f : 0.f;
                    if (eb + j >= d) ii = 0;
                    float4 vv = t4[(size_t)ii * 16 + q];
                    acc.x = fmaf(mm, vv.x, acc.x); acc.y = fmaf(mm, vv.y, acc.y);
                    acc.z = fmaf(mm, vv.z, acc.z); acc.w = fmaf(mm, vv.w, acc.w);
                }
            }
            acc.x += __shfl_xor(acc.x, 16, 64); acc.y += __shfl_xor(acc.y, 16, 64);
            acc.z += __shfl_xor(acc.z, 16, 64); acc.w += __shfl_xor(acc.w, 16, 64);
            acc.x += __shfl_xor(acc.x, 32, 64); acc.y += __shfl_xor(acc.y, 32, 64);
            acc.z += __shfl_xor(acc.z, 32, 64); acc.w += __shfl_xor(acc.w, 32, 64);
            float4 self = t4[(size_t)node * 16 + q];
            const float invv = 1.0f / (float)(d + 1);
            float4 r;
            r.x = fmaxf((acc.x + self.x) * invv + bq.x, 0.f);
            r.y = fmaxf((acc.y + self.y) * invv + bq.y, 0.f);
            r.z = fmaxf((acc.z + self.z) * invv + bq.z, 0.f);
            r.w = fmaxf((acc.w + self.w) * invv + bq.w, 0.f);
            float o0 = 0.f, o1 = 0.f;
#pragma unroll
            for (int c = 0; c < 16; c += 2) {
                float4 w0 = wrow4[c];
                float4 w1 = wrow4[c + 1];
                o0 = fmaf(rl(r.x, c), w0.x, o0);
                o0 = fmaf(rl(r.y, c), w0.y, o0);
                o0 = fmaf(rl(r.z, c), w0.z, o0);
                o0 = fmaf(rl(r.w, c), w0.w, o0);
                o1 = fmaf(rl(r.x, c + 1), w1.x, o1);
                o1 = fmaf(rl(r.y, c + 1), w1.y, o1);
                o1 = fmaf(rl(r.z, c + 1), w1.z, o1);
                o1 = fmaf(rl(r.w, c + 1), w1.w, o1);
            }
            if (has_out) tn[(size_t)node * OUTW + lane] = o0 + o1;
        }
    }
}

// ---- final: out = (seg(t)+t)*inv + b, 40-wide, 2-deep pipeline ----
template <int NPW>
__global__ __launch_bounds__(256) void agg40_k(const float* __restrict__ t,     // [N,40]
                                               const float* __restrict__ bias,  // [40]
                                               const int* __restrict__ deg,
                                               const int* __restrict__ ell,
                                               float* __restrict__ out, int n_nodes) {
    const int lane = threadIdx.x & 63;
    const int wave = (blockIdx.x << 2) | (threadIdx.x >> 6);
    const int g = lane / 10;      // 0..5 active, 6 idle
    const int q = lane - g * 10;  // 0..9
    const bool act = lane < 60;
    const float4* t4 = (const float4*)t;
    const float4 bq = ((const float4*)bias)[q];
    const int node0 = wave * NPW;
    if (node0 >= n_nodes) return;

    int nmax = NPW;
    if (node0 + NPW > n_nodes) nmax = n_nodes - node0;

    int dg[NPW];
#pragma unroll
    for (int k = 0; k < NPW; ++k) dg[k] = deg[node0 + ((k < nmax) ? k : 0)];

    auto eaddr = [&](int nd, int e) -> size_t {
        return (((size_t)(e >> 4) * n_nodes + nd) << 4) + (e & 15);
    };

    float4 vb[2][4];
    float mb[2][4];
    auto issue = [&](int slot, int k) {
        const int node = node0 + k;
        const int d = dg[k];
        const bool k0 = act && (g + 0 < d);
        const bool k1 = act && (g + 6 < d);
        const bool k2 = act && (g + 12 < d);
        const bool k3 = act && (g + 18 < d);
        int i0 = k0 ? ell[eaddr(node, g + 0)] : 0;
        int i1 = k1 ? ell[eaddr(node, g + 6)] : 0;
        int i2 = k2 ? ell[eaddr(node, g + 12)] : 0;
        int i3 = k3 ? ell[eaddr(node, g + 18)] : 0;
        vb[slot][0] = t4[(size_t)i0 * 10 + q];
        vb[slot][1] = t4[(size_t)i1 * 10 + q];
        vb[slot][2] = t4[(size_t)i2 * 10 + q];
        vb[slot][3] = t4[(size_t)i3 * 10 + q];
        mb[slot][0] = k0 ? 1.f : 0.f; mb[slot][1] = k1 ? 1.f : 0.f;
        mb[slot][2] = k2 ? 1.f : 0.f; mb[slot][3] = k3 ? 1.f : 0.f;
    };

    issue(0, 0);
#pragma unroll
    for (int k = 0; k < NPW; ++k) {
        if (k + 1 < NPW) issue((k + 1) & 1, k + 1);
        if (k >= nmax) break;
        const int node = node0 + k;
        const int d = dg[k];
        const float4* v = vb[k & 1];
        const float* m = mb[k & 1];
        float4 acc;
        acc.x = m[0] * v[0].x; acc.y = m[0] * v[0].y;
        acc.z = m[0] * v[0].z; acc.w = m[0] * v[0].w;
        acc.x = fmaf(m[1], v[1].x, acc.x); acc.y = fmaf(m[1], v[1].y, acc.y);
        acc.z = fmaf(m[1], v[1].z, acc.z); acc.w = fmaf(m[1], v[1].w, acc.w);
        acc.x = fmaf(m[2], v[2].x, acc.x); acc.y = fmaf(m[2], v[2].y, acc.y);
        acc.z = fmaf(m[2], v[2].z, acc.z); acc.w = fmaf(m[2], v[2].w, acc.w);
        acc.x = fmaf(m[3], v[3].x, acc.x); acc.y = fmaf(m[3], v[3].y, acc.y);
        acc.z = fmaf(m[3], v[3].z, acc.z); acc.w = fmaf(m[3], v[3].w, acc.w);

        const int dcap = (d < CAP) ? d : CAP;
        for (int u = 1; u * 24 < dcap; ++u) {  // tail (deg > 24)
            const int eb = u * 24 + g;
            const bool k0 = act && (eb + 0 < d) && (eb + 0 < CAP);
            const bool k1 = act && (eb + 6 < d) && (eb + 6 < CAP);
            const bool k2 = act && (eb + 12 < d) && (eb + 12 < CAP);
            const bool k3 = act && (eb + 18 < d) && (eb + 18 < CAP);
            int i0 = k0 ? ell[eaddr(node, eb + 0)] : 0;
            int i1 = k1 ? ell[eaddr(node, eb + 6)] : 0;
            int i2 = k2 ? ell[eaddr(node, eb + 12)] : 0;
            int i3 = k3 ? ell[eaddr(node, eb + 18)] : 0;
            float n0 = k0 ? 1.f : 0.f;
            float n1 = k1 ? 1.f : 0.f;
            float n2 = k2 ? 1.f : 0.f;
            float n3 = k3 ? 1.f : 0.f;
            float4 w0 = t4[(size_t)i0 * 10 + q];
            float4 w1 = t4[(size_t)i1 * 10 + q];
            float4 w2 = t4[(size_t)i2 * 10 + q];
            float4 w3 = t4[(size_t)i3 * 10 + q];
            acc.x = fmaf(n0, w0.x, acc.x); acc.y = fmaf(n0, w0.y, acc.y);
            acc.z = fmaf(n0, w0.z, acc.z); acc.w = fmaf(n0, w0.w, acc.w);
            acc.x = fmaf(n1, w1.x, acc.x); acc.y = fmaf(n1, w1.y, acc.y);
            acc.z = fmaf(n1, w1.z, acc.z); acc.w = fmaf(n1, w1.w, acc.w);
            acc.x = fmaf(n2, w2.x, acc.x); acc.y = fmaf(n2, w2.y, acc.y);
            acc.z = fmaf(n2, w2.z, acc.z); acc.w = fmaf(n2, w2.w, acc.w);
            acc.x = fmaf(n3, w3.x, acc.x); acc.y = fmaf(n3, w3.y, acc.y);
            acc.z = fmaf(n3, w3.z, acc.z); acc.w = fmaf(n3, w3.w, acc.w);
        }

        // fold 6 groups -> group 0
        acc.x += __shfl(acc.x, lane + 30, 64); acc.y += __shfl(acc.y, lane + 30, 64);
        acc.z += __shfl(acc.z, lane + 30, 64); acc.w += __shfl(acc.w, lane + 30, 64);
        float4 s1, s2;
        s1.x = __shfl(acc.x, lane + 10, 64); s2.x = __shfl(acc.x, lane + 20, 64);
        s1.y = __shfl(acc.y, lane + 10, 64); s2.y = __shfl(acc.y, lane + 20, 64);
        s1.z = __shfl(acc.z, lane + 10, 64); s2.z = __shfl(acc.z, lane + 20, 64);
        s1.w = __shfl(acc.w, lane + 10, 64); s2.w = __shfl(acc.w, lane + 20, 64);
        acc.x += s1.x + s2.x; acc.y += s1.y + s2.y;
        acc.z += s1.z + s2.z; acc.w += s1.w + s2.w;

        const float4 self = t4[(size_t)node * 10 + q];
        const float invv = 1.0f / (float)(d + 1);
        float4 r;
        r.x = (acc.x + self.x) * invv + bq.x;
        r.y = (acc.y + self.y) * invv + bq.y;
        r.z = (acc.z + self.z) * invv + bq.z;
        r.w = (acc.w + self.w) * invv + bq.w;
        if (lane < 10) ((float4*)out)[(size_t)node * 10 + q] = r;
    }
}

extern "C" void kernel_launch(void* const* d_in, const int* in_sizes, int n_in,
                              void* d_out, int out_size, void* d_ws, size_t ws_size,
                              hipStream_t stream) {
    const float* feats = (const float*)d_in[0];
    const int*   src   = (const int*)d_in[1];
    const int*   dst   = (const int*)d_in[2];
    const float* W0    = (const float*)d_in[3];
    const float* b0    = (const float*)d_in[4];
    const float* W1    = (const float*)d_in[5];
    const float* b1    = (const float*)d_in[6];
    const float* W2    = (const float*)d_in[7];
    const float* b2    = (const float*)d_in[8];
    float*       out   = (float*)d_out;

    const int N = in_sizes[0] / N_FEAT;  // 100000
    const int E = in_sizes[1];           // 1600000
    const int PB = (E + 255) / 256;      // bin blocks (6250)
    const int NW = PB * 4;               // bin waves (25000)
    const int BS = (N + 7) / 8;          // nodes per bucket (12500)

    // Workspace (~78 MB). bins aliases Y (bins dead before Y's first write).
    char* p = (char*)d_ws;
    float* X   = (float*)p; p += (size_t)N * N_FEAT * sizeof(float);   // 25.6 MB
    float* Y   = (float*)p; p += (size_t)N * N_FEAT * sizeof(float);   // 25.6 MB
    unsigned int* bins = (unsigned int*)Y;  // 8*NW*CAPW*4 = 19.2 MB <= 25.6
    int*   deg = (int*)p;   p += (size_t)(N + 1) * sizeof(int);        // deg + ovf_cnt
    int*   ovf_cnt = deg + N;
    int*   ovf = (int*)p;   p += (size_t)OVF_CAP * 2 * sizeof(int);    // 32 KB
    unsigned long long* cnt64 = (unsigned long long*)p;
    p += (size_t)NW * sizeof(unsigned long long);                      // 200 KB
    int*   ell = (int*)p;   p += (size_t)N * CAP * sizeof(int);        // 25.6 MB

    hipMemsetAsync(deg, 0, (size_t)(N + 1) * sizeof(int), stream);

    constexpr int NPW = 4;
    const int tb = ((N + 7) / 8 + 3) / 4;                 // transform blocks (3125)
    const int ab = ((N + NPW - 1) / NPW + 3) / 4;         // agg blocks (6250)

    // bin_edges || t0 = feats @ W0^T  (independent)
    prep<<<PB + tb, 256, 0, stream>>>(src, dst, bins, cnt64, ovf, ovf_cnt,
                                      E, BS, NW, feats, W0, X, N, PB);
    fill_from_bins<<<2048, 256, 0, stream>>>(bins, cnt64, ovf, ovf_cnt, deg, ell, NW, BS, N);
    // t1 = relu((seg(t0)+t0)*inv + b0) @ W1^T
    agg_t_k<64, NPW><<<ab, 256, 0, stream>>>(X, b0, W1, deg, ell, Y, N);
    // t2 = relu((seg(t1)+t1)*inv + b1) @ W2^T   (40-wide)
    agg_t_k<40, NPW><<<ab, 256, 0, stream>>>(Y, b1, W2, deg, ell, X, N);
    // out = (seg(t2)+t2)*inv + b2
    agg40_k<NPW><<<ab, 256, 0, stream>>>(X, b2, deg, ell, out, N);
}

// Round 3
// 384.880 us; speedup vs baseline: 1.1478x; 1.0147x over previous
//
#include <hip/hip_runtime.h>
#include <hip/hip_bf16.h>

// GraphSAGE (GCN-aggregator) — 3 layers, fp32.
// Structure: transform-then-aggregate ((seg(t)+t)*inv + b, t = h@W^T).
// R10: R9 failed absmax (6.4e-3). Bisect: revert the intra-wave LDS
// h-broadcast (ds_write under divergent predicate -> unbarriered ds_read,
// the only unprovable mechanism) back to the R8-proven readlane broadcast.
// Keep R9's verified parts:
//  (a) 32-slot ELL planes: plane 0 covers deg<=32 (99.99% of nodes) ->
//      all 8 gathers/lane prefetched in the node pipeline.
//  (b) sentinel slots: ell pre-init to index N (zeroed row appended to t)
//      -> maskless adds; init fused into prep.
// fp32 throughout (bf16 would exceed the 7.1e-4 absmax threshold).

#define N_FEAT 64
#define CAP 64    // ELL slots per node (2 planes of 32)
#define CAPW 24   // bin slots per (bucket, wave)
#define OVF_CAP 4096

__device__ __forceinline__ float rl(float v, int l) {
    return __int_as_float(__builtin_amdgcn_readlane(__float_as_int(v), l));
}

// ---- bin_edges body: bin edges by dst bucket (atomic-free, packed cnt) ----
__device__ __forceinline__ void bin_body(const int* __restrict__ src,
                                         const int* __restrict__ dst,
                                         unsigned int* __restrict__ bins,  // [8, nw, CAPW]
                                         unsigned long long* __restrict__ cnt64,  // [nw]
                                         int* __restrict__ ovf, int* __restrict__ ovf_cnt,
                                         int n_edges, int bsize, int nw, int bid) {
    const int e = bid * 256 + threadIdx.x;
    const int lane = threadIdx.x & 63;
    const int wid = (bid << 2) | (threadIdx.x >> 6);
    const bool valid = e < n_edges;
    int s = 0, d = 0;
    if (valid) { s = src[e]; d = dst[e]; }
    const unsigned int bucket = valid ? ((unsigned int)d / (unsigned int)bsize) : 8u;
    const unsigned int local = valid ? (unsigned int)(d - (int)bucket * bsize) : 0u;
    const unsigned int pack = (local << 17) | (unsigned int)s;

    int mycnt = 0;
    for (int c = 0; c < 8; ++c) {
        unsigned long long m = __ballot(valid && bucket == (unsigned int)c);
        int cc = __popcll(m);
        if (lane == c) mycnt = (cc < CAPW) ? cc : CAPW;
        if (valid && bucket == (unsigned int)c) {
            int pfx = __popcll(m & ((1ull << lane) - 1ull));
            if (pfx < CAPW) {
                __builtin_nontemporal_store(pack, &bins[((size_t)c * nw + wid) * CAPW + pfx]);
            } else {
                int p = atomicAdd(ovf_cnt, 1);
                if (p < OVF_CAP) { ovf[2 * p] = s; ovf[2 * p + 1] = d; }
            }
        }
    }
    unsigned long long packed = 0;
#pragma unroll
    for (int c = 0; c < 8; ++c) {
        int v = __builtin_amdgcn_readlane(mycnt, c);
        packed |= ((unsigned long long)(v & 0xFF)) << (8 * c);
    }
    if (lane == 0) cnt64[wid] = packed;
}

// ---- transform body: t[node][o] = sum_f h[node][f] * W[o][f]  (OUT=64) ----
__device__ __forceinline__ void transform64_body(const float* __restrict__ h,
                                                 const float* __restrict__ W,
                                                 float* __restrict__ t, int n_nodes, int bid) {
    const int lane = threadIdx.x & 63;
    const int wave = (bid << 2) | (threadIdx.x >> 6);
    float4 wreg[16];
    const float4* W4 = (const float4*)(W + lane * N_FEAT);
#pragma unroll
    for (int k = 0; k < 16; ++k) wreg[k] = W4[k];
    const float* wf = (const float*)wreg;

    const int node0 = wave * 8;
    for (int k = 0; k < 8; ++k) {
        const int node = node0 + k;
        if (node >= n_nodes) return;  // wave-uniform
        const float hv = h[(size_t)node * N_FEAT + lane];
        float acc = 0.f;
#pragma unroll
        for (int f = 0; f < 64; ++f) acc = fmaf(rl(hv, f), wf[f], acc);
        t[(size_t)node * N_FEAT + lane] = acc;
    }
}

// ---- ell sentinel init + X zero-row ----
__device__ __forceinline__ void ell_init_body(int* __restrict__ ell,
                                              float* __restrict__ xz,
                                              int n_nodes, int bid, int nb) {
    const size_t total4 = (size_t)n_nodes * (CAP / 4);
    int4* e4 = (int4*)ell;
    const int4 sv = make_int4(n_nodes, n_nodes, n_nodes, n_nodes);
    for (size_t i = (size_t)bid * 256 + threadIdx.x; i < total4; i += (size_t)nb * 256)
        e4[i] = sv;
    if (bid == 0 && threadIdx.x < 64) xz[threadIdx.x] = 0.f;  // sentinel row of t0
}

// ---- fused: bin_edges || transform0 || ell-init (block-range split) ----
__global__ __launch_bounds__(256) void prep(const int* __restrict__ src,
                                            const int* __restrict__ dst,
                                            unsigned int* __restrict__ bins,
                                            unsigned long long* __restrict__ cnt64,
                                            int* __restrict__ ovf, int* __restrict__ ovf_cnt,
                                            int n_edges, int bsize, int nw,
                                            const float* __restrict__ feats,
                                            const float* __restrict__ W0,
                                            float* __restrict__ t0, int n_nodes,
                                            int* __restrict__ ell,
                                            int PB, int TB, int IB) {
    const int b = (int)blockIdx.x;
    if (b < PB)
        bin_body(src, dst, bins, cnt64, ovf, ovf_cnt, n_edges, bsize, nw, b);
    else if (b < PB + TB)
        transform64_body(feats, W0, t0, n_nodes, b - PB);
    else
        ell_init_body(ell, t0 + (size_t)n_nodes * N_FEAT, n_nodes, b - PB - TB, IB);
}

// ---- phase 2: scatter bins into plane-split ELL (32-slot planes) ----
__global__ __launch_bounds__(256) void fill_from_bins(const unsigned int* __restrict__ bins,
                                                      const unsigned long long* __restrict__ cnt64,
                                                      const int* __restrict__ ovf,
                                                      const int* __restrict__ ovf_cnt,
                                                      int* __restrict__ deg,
                                                      int* __restrict__ ell,
                                                      int nw, int bsize, int n_nodes) {
    const int lane = threadIdx.x & 63;
    const int w = threadIdx.x >> 6;
    const int c = blockIdx.x & 7;          // bucket -> XCD (round-robin dispatch)
    const int jb = blockIdx.x >> 3;
    const int base_node = c * bsize;
    const int sub = lane >> 3;             // 8 sub-segments per wave
    const int rr = lane & 7;               // record id within tier
    const int wave_in_bucket = jb * 4 + w;
    const int nwaves = (gridDim.x >> 3) * 4;
    const int shift = 8 * c;

    for (int s0 = wave_in_bucket * 8; s0 < nw; s0 += nwaves * 8) {
        const int sg = s0 + sub;
        unsigned long long word = (sg < nw) ? cnt64[sg] : 0ull;  // one 64B line/iter
        const int n = (int)((word >> shift) & 0xFFull);
#pragma unroll
        for (int t = 0; t < 3; ++t) {          // tiers: records 0-7, 8-15, 16-23
            const int rec = t * 8 + rr;
            const bool act = rec < n;
            unsigned long long bm = __ballot(act);
            if (!bm) break;                    // wave-uniform early out
            if (act) {
                unsigned int v = __builtin_nontemporal_load(
                    &bins[((size_t)c * nw + sg) * CAPW + rec]);
                int sv = (int)(v & 0x1FFFFu);
                int d = base_node + (int)(v >> 17);
                int slot = atomicAdd(&deg[d], 1);
                if (slot < CAP)
                    ell[(((size_t)(slot >> 5) * n_nodes + d) << 5) + (slot & 31)] = sv;
            }
        }
    }
    if (blockIdx.x == 0) {  // drain (expected-empty) overflow list
        int n = *ovf_cnt; n = (n < OVF_CAP) ? n : OVF_CAP;
        for (int i = threadIdx.x; i < n; i += 256) {
            int sv = ovf[2 * i], d = ovf[2 * i + 1];
            int slot = atomicAdd(&deg[d], 1);
            if (slot < CAP)
                ell[(((size_t)(slot >> 5) * n_nodes + d) << 5) + (slot & 31)] = sv;
        }
    }
}

// ---- fused agg + next transform:
//   h = relu((seg(t)+t)*inv + b); t_next[node][o] = sum_f h[f]*Wn[o][f]
// 32-slot ELL planes; sentinel slots hold index N (zero row) -> maskless adds.
// Epilogue: h broadcast via readlane (R8-proven); W rows from padded LDS.
template <int OUTW, int NPW>
__global__ __launch_bounds__(256, 4) void agg_t_k(const float* __restrict__ t,
                                                  const float* __restrict__ bias,  // [64]
                                                  const float* __restrict__ Wn,    // [OUTW,64]
                                                  const int* __restrict__ deg,
                                                  const int* __restrict__ ell,
                                                  float* __restrict__ tn,          // [N,OUTW]
                                                  int n_nodes) {
    __shared__ float4 sW[64 * 17];  // rows padded +1 float4 (structural-min banks)
    if (blockIdx.x == 0 && threadIdx.x < OUTW)
        tn[(size_t)n_nodes * OUTW + threadIdx.x] = 0.f;  // sentinel row for next layer
    {
        const float4* Wg = (const float4*)Wn;
        for (int i = threadIdx.x; i < OUTW * 16; i += 256)
            sW[(i >> 4) * 17 + (i & 15)] = Wg[i];
    }
    __syncthreads();

    const int lane = threadIdx.x & 63;
    const int w = threadIdx.x >> 6;
    const int wave = (blockIdx.x << 2) | w;
    const int g = lane >> 4;
    const int q = lane & 15;
    const float4* t4 = (const float4*)t;
    const float4* tq = t4 + q;
    const int4* ell4 = (const int4*)ell;
    const float4 bq = ((const float4*)bias)[q];
    const int wrow = (OUTW == 64) ? lane : ((lane < OUTW) ? lane : 0);
    const float4* wrow4 = sW + wrow * 17;
    const bool has_out = (OUTW == 64) || (lane < OUTW);

    const int node0 = wave * NPW;
    if (node0 >= n_nodes) return;
    const int gi = g * 2;  // int4 pair base within a node's 8 int4 idx words

#define GATH8(V, I)                         \
    do {                                    \
        V[0] = tq[(size_t)(I)[0].x * 16];   \
        V[1] = tq[(size_t)(I)[0].y * 16];   \
        V[2] = tq[(size_t)(I)[0].z * 16];   \
        V[3] = tq[(size_t)(I)[0].w * 16];   \
        V[4] = tq[(size_t)(I)[1].x * 16];   \
        V[5] = tq[(size_t)(I)[1].y * 16];   \
        V[6] = tq[(size_t)(I)[1].z * 16];   \
        V[7] = tq[(size_t)(I)[1].w * 16];   \
    } while (0)

#define EPILOGUE_GEMM(R)                                  \
    float o0 = 0.f, o1 = 0.f;                             \
    _Pragma("unroll")                                     \
    for (int c = 0; c < 16; c += 2) {                     \
        float4 w0 = wrow4[c];                             \
        float4 w1 = wrow4[c + 1];                         \
        o0 = fmaf(rl((R).x, c), w0.x, o0);                \
        o0 = fmaf(rl((R).y, c), w0.y, o0);                \
        o0 = fmaf(rl((R).z, c), w0.z, o0);                \
        o0 = fmaf(rl((R).w, c), w0.w, o0);                \
        o1 = fmaf(rl((R).x, c + 1), w1.x, o1);            \
        o1 = fmaf(rl((R).y, c + 1), w1.y, o1);            \
        o1 = fmaf(rl((R).z, c + 1), w1.z, o1);            \
        o1 = fmaf(rl((R).w, c + 1), w1.w, o1);            \
    }

    if (node0 + NPW <= n_nodes) {
        int dgv[NPW];
#pragma unroll
        for (int k = 0; k < NPW; ++k) dgv[k] = deg[node0 + k];

        int4 ix[2][2];
        float4 vb[2][8];
        float4 selfb[2];
        ix[0][0] = ell4[(size_t)node0 * 8 + gi];
        ix[0][1] = ell4[(size_t)node0 * 8 + gi + 1];
        if (NPW > 1) {
            ix[1][0] = ell4[(size_t)(node0 + 1) * 8 + gi];
            ix[1][1] = ell4[(size_t)(node0 + 1) * 8 + gi + 1];
        }
        selfb[0] = t4[(size_t)node0 * 16 + q];
        GATH8(vb[0], ix[0]);

#pragma unroll
        for (int k = 0; k < NPW; ++k) {
            if (k + 1 < NPW) {  // issue next node's self + 8 gathers
                selfb[(k + 1) & 1] = t4[(size_t)(node0 + k + 1) * 16 + q];
                GATH8(vb[(k + 1) & 1], ix[(k + 1) & 1]);
            }
            if (k + 2 < NPW) {  // refill idx two ahead
                ix[k & 1][0] = ell4[(size_t)(node0 + k + 2) * 8 + gi];
                ix[k & 1][1] = ell4[(size_t)(node0 + k + 2) * 8 + gi + 1];
            }
            const int node = node0 + k;
            const int d = dgv[k];
            const float4* v = vb[k & 1];
            float4 acc;
            acc.x = ((v[0].x + v[1].x) + (v[2].x + v[3].x)) +
                    ((v[4].x + v[5].x) + (v[6].x + v[7].x));
            acc.y = ((v[0].y + v[1].y) + (v[2].y + v[3].y)) +
                    ((v[4].y + v[5].y) + (v[6].y + v[7].y));
            acc.z = ((v[0].z + v[1].z) + (v[2].z + v[3].z)) +
                    ((v[4].z + v[5].z) + (v[6].z + v[7].z));
            acc.w = ((v[0].w + v[1].w) + (v[2].w + v[3].w)) +
                    ((v[4].w + v[5].w) + (v[6].w + v[7].w));

            if (d > 32) {  // plane 1 (rare: P(deg>32) ~ 1e-4)
                int4 j0 = ell4[((size_t)(n_nodes + node)) * 8 + gi];
                int4 j1 = ell4[((size_t)(n_nodes + node)) * 8 + gi + 1];
                {
                    float4 u0 = tq[(size_t)j0.x * 16];
                    float4 u1 = tq[(size_t)j0.y * 16];
                    float4 u2 = tq[(size_t)j0.z * 16];
                    float4 u3 = tq[(size_t)j0.w * 16];
                    acc.x += (u0.x + u1.x) + (u2.x + u3.x);
                    acc.y += (u0.y + u1.y) + (u2.y + u3.y);
                    acc.z += (u0.z + u1.z) + (u2.z + u3.z);
                    acc.w += (u0.w + u1.w) + (u2.w + u3.w);
                }
                {
                    float4 u0 = tq[(size_t)j1.x * 16];
                    float4 u1 = tq[(size_t)j1.y * 16];
                    float4 u2 = tq[(size_t)j1.z * 16];
                    float4 u3 = tq[(size_t)j1.w * 16];
                    acc.x += (u0.x + u1.x) + (u2.x + u3.x);
                    acc.y += (u0.y + u1.y) + (u2.y + u3.y);
                    acc.z += (u0.z + u1.z) + (u2.z + u3.z);
                    acc.w += (u0.w + u1.w) + (u2.w + u3.w);
                }
            }

            acc.x += __shfl_xor(acc.x, 16, 64); acc.y += __shfl_xor(acc.y, 16, 64);
            acc.z += __shfl_xor(acc.z, 16, 64); acc.w += __shfl_xor(acc.w, 16, 64);
            acc.x += __shfl_xor(acc.x, 32, 64); acc.y += __shfl_xor(acc.y, 32, 64);
            acc.z += __shfl_xor(acc.z, 32, 64); acc.w += __shfl_xor(acc.w, 32, 64);

            // h (relu'd, bias'd) — identical in all 4 groups per lane
            const float invv = 1.0f / (float)(d + 1);
            float4 r;
            r.x = fmaxf((acc.x + selfb[k & 1].x) * invv + bq.x, 0.f);
            r.y = fmaxf((acc.y + selfb[k & 1].y) * invv + bq.y, 0.f);
            r.z = fmaxf((acc.z + selfb[k & 1].z) * invv + bq.z, 0.f);
            r.w = fmaxf((acc.w + selfb[k & 1].w) * invv + bq.w, 0.f);

            // t_next[o] = sum_f h[f] * Wn[o][f]; h[4c+j] = readlane(r[j], c)
            EPILOGUE_GEMM(r);
            if (has_out) tn[(size_t)node * OUTW + lane] = o0 + o1;
        }
    } else {
        // generic tail path (not taken for N=100000, NPW=4)
        for (int k = 0; k < NPW; ++k) {
            const int node = node0 + k;
            if (node >= n_nodes) return;
            const int d = deg[node];
            float4 acc = make_float4(0.f, 0.f, 0.f, 0.f);
            const int np = (d > 32) ? 2 : 1;
            for (int p = 0; p < np; ++p) {
                int4 ii[2];
                ii[0] = ell4[((size_t)p * n_nodes + node) * 8 + gi];
                ii[1] = ell4[((size_t)p * n_nodes + node) * 8 + gi + 1];
                float4 vv[8];
                GATH8(vv, ii);
                acc.x += ((vv[0].x + vv[1].x) + (vv[2].x + vv[3].x)) +
                         ((vv[4].x + vv[5].x) + (vv[6].x + vv[7].x));
                acc.y += ((vv[0].y + vv[1].y) + (vv[2].y + vv[3].y)) +
                         ((vv[4].y + vv[5].y) + (vv[6].y + vv[7].y));
                acc.z += ((vv[0].z + vv[1].z) + (vv[2].z + vv[3].z)) +
                         ((vv[4].z + vv[5].z) + (vv[6].z + vv[7].z));
                acc.w += ((vv[0].w + vv[1].w) + (vv[2].w + vv[3].w)) +
                         ((vv[4].w + vv[5].w) + (vv[6].w + vv[7].w));
            }
            acc.x += __shfl_xor(acc.x, 16, 64); acc.y += __shfl_xor(acc.y, 16, 64);
            acc.z += __shfl_xor(acc.z, 16, 64); acc.w += __shfl_xor(acc.w, 16, 64);
            acc.x += __shfl_xor(acc.x, 32, 64); acc.y += __shfl_xor(acc.y, 32, 64);
            acc.z += __shfl_xor(acc.z, 32, 64); acc.w += __shfl_xor(acc.w, 32, 64);
            float4 self = t4[(size_t)node * 16 + q];
            const float invv = 1.0f / (float)(d + 1);
            float4 r;
            r.x = fmaxf((acc.x + self.x) * invv + bq.x, 0.f);
            r.y = fmaxf((acc.y + self.y) * invv + bq.y, 0.f);
            r.z = fmaxf((acc.z + self.z) * invv + bq.z, 0.f);
            r.w = fmaxf((acc.w + self.w) * invv + bq.w, 0.f);
            EPILOGUE_GEMM(r);
            if (has_out) tn[(size_t)node * OUTW + lane] = o0 + o1;
        }
    }
#undef GATH8
#undef EPILOGUE_GEMM
}

// ---- final: out = (seg(t)+t)*inv + b, 40-wide, 2-deep pipeline ----
template <int NPW>
__global__ __launch_bounds__(256) void agg40_k(const float* __restrict__ t,     // [N,40]
                                               const float* __restrict__ bias,  // [40]
                                               const int* __restrict__ deg,
                                               const int* __restrict__ ell,
                                               float* __restrict__ out, int n_nodes) {
    const int lane = threadIdx.x & 63;
    const int wave = (blockIdx.x << 2) | (threadIdx.x >> 6);
    const int g = lane / 10;      // 0..5 active, 6 idle
    const int q = lane - g * 10;  // 0..9
    const bool act = lane < 60;
    const float actf = act ? 1.f : 0.f;
    const float4* t4 = (const float4*)t;
    const float4 bq = ((const float4*)bias)[q];
    const int node0 = wave * NPW;
    if (node0 >= n_nodes) return;

    int nmax = NPW;
    if (node0 + NPW > n_nodes) nmax = n_nodes - node0;

    int dg[NPW];
#pragma unroll
    for (int k = 0; k < NPW; ++k) dg[k] = deg[node0 + ((k < nmax) ? k : 0)];

    auto eaddr = [&](int nd, int e) -> size_t {
        return (((size_t)(e >> 5) * n_nodes + nd) << 5) + (e & 31);
    };

    float4 vb[2][4];
    auto issue = [&](int slot, int k) {
        const int node = node0 + k;
        int i0 = ell[eaddr(node, g + 0)];    // sentinel slots -> zero row
        int i1 = ell[eaddr(node, g + 6)];
        int i2 = ell[eaddr(node, g + 12)];
        int i3 = ell[eaddr(node, g + 18)];
        vb[slot][0] = t4[(size_t)i0 * 10 + q];
        vb[slot][1] = t4[(size_t)i1 * 10 + q];
        vb[slot][2] = t4[(size_t)i2 * 10 + q];
        vb[slot][3] = t4[(size_t)i3 * 10 + q];
    };

    issue(0, 0);
#pragma unroll
    for (int k = 0; k < NPW; ++k) {
        if (k + 1 < NPW) issue((k + 1) & 1, k + 1);
        if (k >= nmax) break;
        const int node = node0 + k;
        const int d = dg[k];
        const float4* v = vb[k & 1];
        float4 acc;
        acc.x = (v[0].x + v[1].x) + (v[2].x + v[3].x);
        acc.y = (v[0].y + v[1].y) + (v[2].y + v[3].y);
        acc.z = (v[0].z + v[1].z) + (v[2].z + v[3].z);
        acc.w = (v[0].w + v[1].w) + (v[2].w + v[3].w);

        const int dcap = (d < CAP) ? d : CAP;
        for (int u = 1; u * 24 < dcap; ++u) {  // tail (deg > 24); keep CAP clamps
            const int eb = u * 24 + g;
            const bool k0 = act && (eb + 0 < d) && (eb + 0 < CAP);
            const bool k1 = act && (eb + 6 < d) && (eb + 6 < CAP);
            const bool k2 = act && (eb + 12 < d) && (eb + 12 < CAP);
            const bool k3 = act && (eb + 18 < d) && (eb + 18 < CAP);
            int i0 = k0 ? ell[eaddr(node, eb + 0)] : n_nodes;
            int i1 = k1 ? ell[eaddr(node, eb + 6)] : n_nodes;
            int i2 = k2 ? ell[eaddr(node, eb + 12)] : n_nodes;
            int i3 = k3 ? ell[eaddr(node, eb + 18)] : n_nodes;
            float4 w0 = t4[(size_t)i0 * 10 + q];
            float4 w1 = t4[(size_t)i1 * 10 + q];
            float4 w2 = t4[(size_t)i2 * 10 + q];
            float4 w3 = t4[(size_t)i3 * 10 + q];
            acc.x += (w0.x + w1.x) + (w2.x + w3.x);
            acc.y += (w0.y + w1.y) + (w2.y + w3.y);
            acc.z += (w0.z + w1.z) + (w2.z + w3.z);
            acc.w += (w0.w + w1.w) + (w2.w + w3.w);
        }

        // zero inactive-lane (g==6) contributions, then fold 6 groups -> group 0
        acc.x *= actf; acc.y *= actf; acc.z *= actf; acc.w *= actf;
        acc.x += __shfl(acc.x, lane + 30, 64); acc.y += __shfl(acc.y, lane + 30, 64);
        acc.z += __shfl(acc.z, lane + 30, 64); acc.w += __shfl(acc.w, lane + 30, 64);
        float4 s1, s2;
        s1.x = __shfl(acc.x, lane + 10, 64); s2.x = __shfl(acc.x, lane + 20, 64);
        s1.y = __shfl(acc.y, lane + 10, 64); s2.y = __shfl(acc.y, lane + 20, 64);
        s1.z = __shfl(acc.z, lane + 10, 64); s2.z = __shfl(acc.z, lane + 20, 64);
        s1.w = __shfl(acc.w, lane + 10, 64); s2.w = __shfl(acc.w, lane + 20, 64);
        acc.x += s1.x + s2.x; acc.y += s1.y + s2.y;
        acc.z += s1.z + s2.z; acc.w += s1.w + s2.w;

        const float4 self = t4[(size_t)node * 10 + q];
        const float invv = 1.0f / (float)(d + 1);
        float4 r;
        r.x = (acc.x + self.x) * invv + bq.x;
        r.y = (acc.y + self.y) * invv + bq.y;
        r.z = (acc.z + self.z) * invv + bq.z;
        r.w = (acc.w + self.w) * invv + bq.w;
        if (lane < 10) ((float4*)out)[(size_t)node * 10 + q] = r;
    }
}

extern "C" void kernel_launch(void* const* d_in, const int* in_sizes, int n_in,
                              void* d_out, int out_size, void* d_ws, size_t ws_size,
                              hipStream_t stream) {
    const float* feats = (const float*)d_in[0];
    const int*   src   = (const int*)d_in[1];
    const int*   dst   = (const int*)d_in[2];
    const float* W0    = (const float*)d_in[3];
    const float* b0    = (const float*)d_in[4];
    const float* W1    = (const float*)d_in[5];
    const float* b1    = (const float*)d_in[6];
    const float* W2    = (const float*)d_in[7];
    const float* b2    = (const float*)d_in[8];
    float*       out   = (float*)d_out;

    const int N = in_sizes[0] / N_FEAT;  // 100000
    const int E = in_sizes[1];           // 1600000
    const int PB = (E + 255) / 256;      // bin blocks (6250)
    const int NW = PB * 4;               // bin waves (25000)
    const int BS = (N + 7) / 8;          // nodes per bucket (12500)

    // Workspace (~78 MB). X,Y have one extra 64-float sentinel row.
    // bins aliases Y's head (bins dead before Y's first write).
    char* p = (char*)d_ws;
    float* X   = (float*)p; p += ((size_t)N * N_FEAT + 64) * sizeof(float);  // 25.6 MB
    float* Y   = (float*)p; p += ((size_t)N * N_FEAT + 64) * sizeof(float);  // 25.6 MB
    unsigned int* bins = (unsigned int*)Y;  // 8*NW*CAPW*4 = 19.2 MB <= 25.6
    int*   deg = (int*)p;   p += (size_t)(N + 4) * sizeof(int);        // deg + ovf_cnt (16B-pad)
    int*   ovf_cnt = deg + N;
    int*   ovf = (int*)p;   p += (size_t)OVF_CAP * 2 * sizeof(int);    // 32 KB
    unsigned long long* cnt64 = (unsigned long long*)p;
    p += (size_t)NW * sizeof(unsigned long long);                      // 200 KB
    int*   ell = (int*)p;   p += (size_t)N * CAP * sizeof(int);        // 25.6 MB

    hipMemsetAsync(deg, 0, (size_t)(N + 1) * sizeof(int), stream);

    constexpr int NPW = 4;
    const int TB = ((N + 7) / 8 + 3) / 4;                 // transform blocks (3125)
    const int IB = 1024;                                  // ell-init blocks
    const int ab = ((N + NPW - 1) / NPW + 3) / 4;         // agg blocks (6250)

    // bin_edges || t0 = feats @ W0^T || ell-sentinel init  (independent)
    prep<<<PB + TB + IB, 256, 0, stream>>>(src, dst, bins, cnt64, ovf, ovf_cnt,
                                           E, BS, NW, feats, W0, X, N, ell, PB, TB, IB);
    fill_from_bins<<<2048, 256, 0, stream>>>(bins, cnt64, ovf, ovf_cnt, deg, ell, NW, BS, N);
    // t1 = relu((seg(t0)+t0)*inv + b0) @ W1^T   (writes Y + Y's sentinel row)
    agg_t_k<64, NPW><<<ab, 256, 0, stream>>>(X, b0, W1, deg, ell, Y, N);
    // t2 = relu((seg(t1)+t1)*inv + b1) @ W2^T   (40-wide; writes X + X40 sentinel row)
    agg_t_k<40, NPW><<<ab, 256, 0, stream>>>(Y, b1, W2, deg, ell, X, N);
    // out = (seg(t2)+t2)*inv + b2
    agg40_k<NPW><<<ab, 256, 0, stream>>>(X, b2, deg, ell, out, N);
}

// Round 4
// 383.957 us; speedup vs baseline: 1.1506x; 1.0024x over previous
//
#include <hip/hip_runtime.h>
#include <hip/hip_bf16.h>

// GraphSAGE (GCN-aggregator) — 3 layers, fp32.
// Structure: transform-then-aggregate ((seg(t)+t)*inv + b, t = h@W^T).
// R11: fill_from_bins is now the top dispatch (72us) with VALUBusy 2.5%,
// HBM 13.6% — stalled on device-scope atomicAdd(deg[d]): dense deg puts
// 16 counters per 64B line x mean-deg 16 = 256 serialized memory-side RMWs
// per line (WRITE_SIZE 65MB ~= atomic traffic). Fix: pad deg to one
// counter per 64B line (deg[d<<4], 6.4MB) -> 16x less per-line
// serialization, 16x more line parallelism. Consumers read deg[node<<4].
// Carried from R10: 32-slot ELL planes (all gathers prefetched), sentinel
// slots -> maskless adds, readlane h-broadcast epilogue, W in padded LDS.
// fp32 throughout (bf16 would exceed the 7.1e-4 absmax threshold).

#define N_FEAT 64
#define CAP 64    // ELL slots per node (2 planes of 32)
#define CAPW 24   // bin slots per (bucket, wave)
#define OVF_CAP 4096
#define DEGS 16   // deg counter stride (ints) = one 64B line per node

__device__ __forceinline__ float rl(float v, int l) {
    return __int_as_float(__builtin_amdgcn_readlane(__float_as_int(v), l));
}

// ---- bin_edges body: bin edges by dst bucket (atomic-free, packed cnt) ----
__device__ __forceinline__ void bin_body(const int* __restrict__ src,
                                         const int* __restrict__ dst,
                                         unsigned int* __restrict__ bins,  // [8, nw, CAPW]
                                         unsigned long long* __restrict__ cnt64,  // [nw]
                                         int* __restrict__ ovf, int* __restrict__ ovf_cnt,
                                         int n_edges, int bsize, int nw, int bid) {
    const int e = bid * 256 + threadIdx.x;
    const int lane = threadIdx.x & 63;
    const int wid = (bid << 2) | (threadIdx.x >> 6);
    const bool valid = e < n_edges;
    int s = 0, d = 0;
    if (valid) { s = src[e]; d = dst[e]; }
    const unsigned int bucket = valid ? ((unsigned int)d / (unsigned int)bsize) : 8u;
    const unsigned int local = valid ? (unsigned int)(d - (int)bucket * bsize) : 0u;
    const unsigned int pack = (local << 17) | (unsigned int)s;

    int mycnt = 0;
    for (int c = 0; c < 8; ++c) {
        unsigned long long m = __ballot(valid && bucket == (unsigned int)c);
        int cc = __popcll(m);
        if (lane == c) mycnt = (cc < CAPW) ? cc : CAPW;
        if (valid && bucket == (unsigned int)c) {
            int pfx = __popcll(m & ((1ull << lane) - 1ull));
            if (pfx < CAPW) {
                __builtin_nontemporal_store(pack, &bins[((size_t)c * nw + wid) * CAPW + pfx]);
            } else {
                int p = atomicAdd(ovf_cnt, 1);
                if (p < OVF_CAP) { ovf[2 * p] = s; ovf[2 * p + 1] = d; }
            }
        }
    }
    unsigned long long packed = 0;
#pragma unroll
    for (int c = 0; c < 8; ++c) {
        int v = __builtin_amdgcn_readlane(mycnt, c);
        packed |= ((unsigned long long)(v & 0xFF)) << (8 * c);
    }
    if (lane == 0) cnt64[wid] = packed;
}

// ---- transform body: t[node][o] = sum_f h[node][f] * W[o][f]  (OUT=64) ----
__device__ __forceinline__ void transform64_body(const float* __restrict__ h,
                                                 const float* __restrict__ W,
                                                 float* __restrict__ t, int n_nodes, int bid) {
    const int lane = threadIdx.x & 63;
    const int wave = (bid << 2) | (threadIdx.x >> 6);
    float4 wreg[16];
    const float4* W4 = (const float4*)(W + lane * N_FEAT);
#pragma unroll
    for (int k = 0; k < 16; ++k) wreg[k] = W4[k];
    const float* wf = (const float*)wreg;

    const int node0 = wave * 8;
    for (int k = 0; k < 8; ++k) {
        const int node = node0 + k;
        if (node >= n_nodes) return;  // wave-uniform
        const float hv = h[(size_t)node * N_FEAT + lane];
        float acc = 0.f;
#pragma unroll
        for (int f = 0; f < 64; ++f) acc = fmaf(rl(hv, f), wf[f], acc);
        t[(size_t)node * N_FEAT + lane] = acc;
    }
}

// ---- ell sentinel init + X zero-row ----
__device__ __forceinline__ void ell_init_body(int* __restrict__ ell,
                                              float* __restrict__ xz,
                                              int n_nodes, int bid, int nb) {
    const size_t total4 = (size_t)n_nodes * (CAP / 4);
    int4* e4 = (int4*)ell;
    const int4 sv = make_int4(n_nodes, n_nodes, n_nodes, n_nodes);
    for (size_t i = (size_t)bid * 256 + threadIdx.x; i < total4; i += (size_t)nb * 256)
        e4[i] = sv;
    if (bid == 0 && threadIdx.x < 64) xz[threadIdx.x] = 0.f;  // sentinel row of t0
}

// ---- fused: bin_edges || transform0 || ell-init (block-range split) ----
__global__ __launch_bounds__(256) void prep(const int* __restrict__ src,
                                            const int* __restrict__ dst,
                                            unsigned int* __restrict__ bins,
                                            unsigned long long* __restrict__ cnt64,
                                            int* __restrict__ ovf, int* __restrict__ ovf_cnt,
                                            int n_edges, int bsize, int nw,
                                            const float* __restrict__ feats,
                                            const float* __restrict__ W0,
                                            float* __restrict__ t0, int n_nodes,
                                            int* __restrict__ ell,
                                            int PB, int TB, int IB) {
    const int b = (int)blockIdx.x;
    if (b < PB)
        bin_body(src, dst, bins, cnt64, ovf, ovf_cnt, n_edges, bsize, nw, b);
    else if (b < PB + TB)
        transform64_body(feats, W0, t0, n_nodes, b - PB);
    else
        ell_init_body(ell, t0 + (size_t)n_nodes * N_FEAT, n_nodes, b - PB - TB, IB);
}

// ---- phase 2: scatter bins into plane-split ELL (32-slot planes) ----
// deg counters padded to one per 64B line: deg[d << 4].
__global__ __launch_bounds__(256) void fill_from_bins(const unsigned int* __restrict__ bins,
                                                      const unsigned long long* __restrict__ cnt64,
                                                      const int* __restrict__ ovf,
                                                      const int* __restrict__ ovf_cnt,
                                                      int* __restrict__ deg,
                                                      int* __restrict__ ell,
                                                      int nw, int bsize, int n_nodes) {
    const int lane = threadIdx.x & 63;
    const int w = threadIdx.x >> 6;
    const int c = blockIdx.x & 7;          // bucket -> XCD (round-robin dispatch)
    const int jb = blockIdx.x >> 3;
    const int base_node = c * bsize;
    const int sub = lane >> 3;             // 8 sub-segments per wave
    const int rr = lane & 7;               // record id within tier
    const int wave_in_bucket = jb * 4 + w;
    const int nwaves = (gridDim.x >> 3) * 4;
    const int shift = 8 * c;

    for (int s0 = wave_in_bucket * 8; s0 < nw; s0 += nwaves * 8) {
        const int sg = s0 + sub;
        unsigned long long word = (sg < nw) ? cnt64[sg] : 0ull;  // one 64B line/iter
        const int n = (int)((word >> shift) & 0xFFull);
#pragma unroll
        for (int t = 0; t < 3; ++t) {          // tiers: records 0-7, 8-15, 16-23
            const int rec = t * 8 + rr;
            const bool act = rec < n;
            unsigned long long bm = __ballot(act);
            if (!bm) break;                    // wave-uniform early out
            if (act) {
                unsigned int v = __builtin_nontemporal_load(
                    &bins[((size_t)c * nw + sg) * CAPW + rec]);
                int sv = (int)(v & 0x1FFFFu);
                int d = base_node + (int)(v >> 17);
                int slot = atomicAdd(&deg[(size_t)d << 4], 1);
                if (slot < CAP)
                    ell[(((size_t)(slot >> 5) * n_nodes + d) << 5) + (slot & 31)] = sv;
            }
        }
    }
    if (blockIdx.x == 0) {  // drain (expected-empty) overflow list
        int n = *ovf_cnt; n = (n < OVF_CAP) ? n : OVF_CAP;
        for (int i = threadIdx.x; i < n; i += 256) {
            int sv = ovf[2 * i], d = ovf[2 * i + 1];
            int slot = atomicAdd(&deg[(size_t)d << 4], 1);
            if (slot < CAP)
                ell[(((size_t)(slot >> 5) * n_nodes + d) << 5) + (slot & 31)] = sv;
        }
    }
}

// ---- fused agg + next transform:
//   h = relu((seg(t)+t)*inv + b); t_next[node][o] = sum_f h[f]*Wn[o][f]
// 32-slot ELL planes; sentinel slots hold index N (zero row) -> maskless adds.
// Epilogue: h broadcast via readlane (R8-proven); W rows from padded LDS.
template <int OUTW, int NPW>
__global__ __launch_bounds__(256, 4) void agg_t_k(const float* __restrict__ t,
                                                  const float* __restrict__ bias,  // [64]
                                                  const float* __restrict__ Wn,    // [OUTW,64]
                                                  const int* __restrict__ deg,     // [N<<4] padded
                                                  const int* __restrict__ ell,
                                                  float* __restrict__ tn,          // [N,OUTW]
                                                  int n_nodes) {
    __shared__ float4 sW[64 * 17];  // rows padded +1 float4 (structural-min banks)
    if (blockIdx.x == 0 && threadIdx.x < OUTW)
        tn[(size_t)n_nodes * OUTW + threadIdx.x] = 0.f;  // sentinel row for next layer
    {
        const float4* Wg = (const float4*)Wn;
        for (int i = threadIdx.x; i < OUTW * 16; i += 256)
            sW[(i >> 4) * 17 + (i & 15)] = Wg[i];
    }
    __syncthreads();

    const int lane = threadIdx.x & 63;
    const int w = threadIdx.x >> 6;
    const int wave = (blockIdx.x << 2) | w;
    const int g = lane >> 4;
    const int q = lane & 15;
    const float4* t4 = (const float4*)t;
    const float4* tq = t4 + q;
    const int4* ell4 = (const int4*)ell;
    const float4 bq = ((const float4*)bias)[q];
    const int wrow = (OUTW == 64) ? lane : ((lane < OUTW) ? lane : 0);
    const float4* wrow4 = sW + wrow * 17;
    const bool has_out = (OUTW == 64) || (lane < OUTW);

    const int node0 = wave * NPW;
    if (node0 >= n_nodes) return;
    const int gi = g * 2;  // int4 pair base within a node's 8 int4 idx words

#define GATH8(V, I)                         \
    do {                                    \
        V[0] = tq[(size_t)(I)[0].x * 16];   \
        V[1] = tq[(size_t)(I)[0].y * 16];   \
        V[2] = tq[(size_t)(I)[0].z * 16];   \
        V[3] = tq[(size_t)(I)[0].w * 16];   \
        V[4] = tq[(size_t)(I)[1].x * 16];   \
        V[5] = tq[(size_t)(I)[1].y * 16];   \
        V[6] = tq[(size_t)(I)[1].z * 16];   \
        V[7] = tq[(size_t)(I)[1].w * 16];   \
    } while (0)

#define EPILOGUE_GEMM(R)                                  \
    float o0 = 0.f, o1 = 0.f;                             \
    _Pragma("unroll")                                     \
    for (int c = 0; c < 16; c += 2) {                     \
        float4 w0 = wrow4[c];                             \
        float4 w1 = wrow4[c + 1];                         \
        o0 = fmaf(rl((R).x, c), w0.x, o0);                \
        o0 = fmaf(rl((R).y, c), w0.y, o0);                \
        o0 = fmaf(rl((R).z, c), w0.z, o0);                \
        o0 = fmaf(rl((R).w, c), w0.w, o0);                \
        o1 = fmaf(rl((R).x, c + 1), w1.x, o1);            \
        o1 = fmaf(rl((R).y, c + 1), w1.y, o1);            \
        o1 = fmaf(rl((R).z, c + 1), w1.z, o1);            \
        o1 = fmaf(rl((R).w, c + 1), w1.w, o1);            \
    }

    if (node0 + NPW <= n_nodes) {
        int dgv[NPW];
#pragma unroll
        for (int k = 0; k < NPW; ++k) dgv[k] = deg[(size_t)(node0 + k) << 4];

        int4 ix[2][2];
        float4 vb[2][8];
        float4 selfb[2];
        ix[0][0] = ell4[(size_t)node0 * 8 + gi];
        ix[0][1] = ell4[(size_t)node0 * 8 + gi + 1];
        if (NPW > 1) {
            ix[1][0] = ell4[(size_t)(node0 + 1) * 8 + gi];
            ix[1][1] = ell4[(size_t)(node0 + 1) * 8 + gi + 1];
        }
        selfb[0] = t4[(size_t)node0 * 16 + q];
        GATH8(vb[0], ix[0]);

#pragma unroll
        for (int k = 0; k < NPW; ++k) {
            if (k + 1 < NPW) {  // issue next node's self + 8 gathers
                selfb[(k + 1) & 1] = t4[(size_t)(node0 + k + 1) * 16 + q];
                GATH8(vb[(k + 1) & 1], ix[(k + 1) & 1]);
            }
            if (k + 2 < NPW) {  // refill idx two ahead
                ix[k & 1][0] = ell4[(size_t)(node0 + k + 2) * 8 + gi];
                ix[k & 1][1] = ell4[(size_t)(node0 + k + 2) * 8 + gi + 1];
            }
            const int node = node0 + k;
            const int d = dgv[k];
            const float4* v = vb[k & 1];
            float4 acc;
            acc.x = ((v[0].x + v[1].x) + (v[2].x + v[3].x)) +
                    ((v[4].x + v[5].x) + (v[6].x + v[7].x));
            acc.y = ((v[0].y + v[1].y) + (v[2].y + v[3].y)) +
                    ((v[4].y + v[5].y) + (v[6].y + v[7].y));
            acc.z = ((v[0].z + v[1].z) + (v[2].z + v[3].z)) +
                    ((v[4].z + v[5].z) + (v[6].z + v[7].z));
            acc.w = ((v[0].w + v[1].w) + (v[2].w + v[3].w)) +
                    ((v[4].w + v[5].w) + (v[6].w + v[7].w));

            if (d > 32) {  // plane 1 (rare: P(deg>32) ~ 1e-4)
                int4 j0 = ell4[((size_t)(n_nodes + node)) * 8 + gi];
                int4 j1 = ell4[((size_t)(n_nodes + node)) * 8 + gi + 1];
                {
                    float4 u0 = tq[(size_t)j0.x * 16];
                    float4 u1 = tq[(size_t)j0.y * 16];
                    float4 u2 = tq[(size_t)j0.z * 16];
                    float4 u3 = tq[(size_t)j0.w * 16];
                    acc.x += (u0.x + u1.x) + (u2.x + u3.x);
                    acc.y += (u0.y + u1.y) + (u2.y + u3.y);
                    acc.z += (u0.z + u1.z) + (u2.z + u3.z);
                    acc.w += (u0.w + u1.w) + (u2.w + u3.w);
                }
                {
                    float4 u0 = tq[(size_t)j1.x * 16];
                    float4 u1 = tq[(size_t)j1.y * 16];
                    float4 u2 = tq[(size_t)j1.z * 16];
                    float4 u3 = tq[(size_t)j1.w * 16];
                    acc.x += (u0.x + u1.x) + (u2.x + u3.x);
                    acc.y += (u0.y + u1.y) + (u2.y + u3.y);
                    acc.z += (u0.z + u1.z) + (u2.z + u3.z);
                    acc.w += (u0.w + u1.w) + (u2.w + u3.w);
                }
            }

            acc.x += __shfl_xor(acc.x, 16, 64); acc.y += __shfl_xor(acc.y, 16, 64);
            acc.z += __shfl_xor(acc.z, 16, 64); acc.w += __shfl_xor(acc.w, 16, 64);
            acc.x += __shfl_xor(acc.x, 32, 64); acc.y += __shfl_xor(acc.y, 32, 64);
            acc.z += __shfl_xor(acc.z, 32, 64); acc.w += __shfl_xor(acc.w, 32, 64);

            // h (relu'd, bias'd) — identical in all 4 groups per lane
            const float invv = 1.0f / (float)(d + 1);
            float4 r;
            r.x = fmaxf((acc.x + selfb[k & 1].x) * invv + bq.x, 0.f);
            r.y = fmaxf((acc.y + selfb[k & 1].y) * invv + bq.y, 0.f);
            r.z = fmaxf((acc.z + selfb[k & 1].z) * invv + bq.z, 0.f);
            r.w = fmaxf((acc.w + selfb[k & 1].w) * invv + bq.w, 0.f);

            // t_next[o] = sum_f h[f] * Wn[o][f]; h[4c+j] = readlane(r[j], c)
            EPILOGUE_GEMM(r);
            if (has_out) tn[(size_t)node * OUTW + lane] = o0 + o1;
        }
    } else {
        // generic tail path (not taken for N=100000, NPW=4)
        for (int k = 0; k < NPW; ++k) {
            const int node = node0 + k;
            if (node >= n_nodes) return;
            const int d = deg[(size_t)node << 4];
            float4 acc = make_float4(0.f, 0.f, 0.f, 0.f);
            const int np = (d > 32) ? 2 : 1;
            for (int p = 0; p < np; ++p) {
                int4 ii[2];
                ii[0] = ell4[((size_t)p * n_nodes + node) * 8 + gi];
                ii[1] = ell4[((size_t)p * n_nodes + node) * 8 + gi + 1];
                float4 vv[8];
                GATH8(vv, ii);
                acc.x += ((vv[0].x + vv[1].x) + (vv[2].x + vv[3].x)) +
                         ((vv[4].x + vv[5].x) + (vv[6].x + vv[7].x));
                acc.y += ((vv[0].y + vv[1].y) + (vv[2].y + vv[3].y)) +
                         ((vv[4].y + vv[5].y) + (vv[6].y + vv[7].y));
                acc.z += ((vv[0].z + vv[1].z) + (vv[2].z + vv[3].z)) +
                         ((vv[4].z + vv[5].z) + (vv[6].z + vv[7].z));
                acc.w += ((vv[0].w + vv[1].w) + (vv[2].w + vv[3].w)) +
                         ((vv[4].w + vv[5].w) + (vv[6].w + vv[7].w));
            }
            acc.x += __shfl_xor(acc.x, 16, 64); acc.y += __shfl_xor(acc.y, 16, 64);
            acc.z += __shfl_xor(acc.z, 16, 64); acc.w += __shfl_xor(acc.w, 16, 64);
            acc.x += __shfl_xor(acc.x, 32, 64); acc.y += __shfl_xor(acc.y, 32, 64);
            acc.z += __shfl_xor(acc.z, 32, 64); acc.w += __shfl_xor(acc.w, 32, 64);
            float4 self = t4[(size_t)node * 16 + q];
            const float invv = 1.0f / (float)(d + 1);
            float4 r;
            r.x = fmaxf((acc.x + self.x) * invv + bq.x, 0.f);
            r.y = fmaxf((acc.y + self.y) * invv + bq.y, 0.f);
            r.z = fmaxf((acc.z + self.z) * invv + bq.z, 0.f);
            r.w = fmaxf((acc.w + self.w) * invv + bq.w, 0.f);
            EPILOGUE_GEMM(r);
            if (has_out) tn[(size_t)node * OUTW + lane] = o0 + o1;
        }
    }
#undef GATH8
#undef EPILOGUE_GEMM
}

// ---- final: out = (seg(t)+t)*inv + b, 40-wide, 2-deep pipeline ----
template <int NPW>
__global__ __launch_bounds__(256) void agg40_k(const float* __restrict__ t,     // [N,40]
                                               const float* __restrict__ bias,  // [40]
                                               const int* __restrict__ deg,     // [N<<4] padded
                                               const int* __restrict__ ell,
                                               float* __restrict__ out, int n_nodes) {
    const int lane = threadIdx.x & 63;
    const int wave = (blockIdx.x << 2) | (threadIdx.x >> 6);
    const int g = lane / 10;      // 0..5 active, 6 idle
    const int q = lane - g * 10;  // 0..9
    const bool act = lane < 60;
    const float actf = act ? 1.f : 0.f;
    const float4* t4 = (const float4*)t;
    const float4 bq = ((const float4*)bias)[q];
    const int node0 = wave * NPW;
    if (node0 >= n_nodes) return;

    int nmax = NPW;
    if (node0 + NPW > n_nodes) nmax = n_nodes - node0;

    int dg[NPW];
#pragma unroll
    for (int k = 0; k < NPW; ++k) dg[k] = deg[(size_t)(node0 + ((k < nmax) ? k : 0)) << 4];

    auto eaddr = [&](int nd, int e) -> size_t {
        return (((size_t)(e >> 5) * n_nodes + nd) << 5) + (e & 31);
    };

    float4 vb[2][4];
    auto issue = [&](int slot, int k) {
        const int node = node0 + k;
        int i0 = ell[eaddr(node, g + 0)];    // sentinel slots -> zero row
        int i1 = ell[eaddr(node, g + 6)];
        int i2 = ell[eaddr(node, g + 12)];
        int i3 = ell[eaddr(node, g + 18)];
        vb[slot][0] = t4[(size_t)i0 * 10 + q];
        vb[slot][1] = t4[(size_t)i1 * 10 + q];
        vb[slot][2] = t4[(size_t)i2 * 10 + q];
        vb[slot][3] = t4[(size_t)i3 * 10 + q];
    };

    issue(0, 0);
#pragma unroll
    for (int k = 0; k < NPW; ++k) {
        if (k + 1 < NPW) issue((k + 1) & 1, k + 1);
        if (k >= nmax) break;
        const int node = node0 + k;
        const int d = dg[k];
        const float4* v = vb[k & 1];
        float4 acc;
        acc.x = (v[0].x + v[1].x) + (v[2].x + v[3].x);
        acc.y = (v[0].y + v[1].y) + (v[2].y + v[3].y);
        acc.z = (v[0].z + v[1].z) + (v[2].z + v[3].z);
        acc.w = (v[0].w + v[1].w) + (v[2].w + v[3].w);

        const int dcap = (d < CAP) ? d : CAP;
        for (int u = 1; u * 24 < dcap; ++u) {  // tail (deg > 24); keep CAP clamps
            const int eb = u * 24 + g;
            const bool k0 = act && (eb + 0 < d) && (eb + 0 < CAP);
            const bool k1 = act && (eb + 6 < d) && (eb + 6 < CAP);
            const bool k2 = act && (eb + 12 < d) && (eb + 12 < CAP);
            const bool k3 = act && (eb + 18 < d) && (eb + 18 < CAP);
            int i0 = k0 ? ell[eaddr(node, eb + 0)] : n_nodes;
            int i1 = k1 ? ell[eaddr(node, eb + 6)] : n_nodes;
            int i2 = k2 ? ell[eaddr(node, eb + 12)] : n_nodes;
            int i3 = k3 ? ell[eaddr(node, eb + 18)] : n_nodes;
            float4 w0 = t4[(size_t)i0 * 10 + q];
            float4 w1 = t4[(size_t)i1 * 10 + q];
            float4 w2 = t4[(size_t)i2 * 10 + q];
            float4 w3 = t4[(size_t)i3 * 10 + q];
            acc.x += (w0.x + w1.x) + (w2.x + w3.x);
            acc.y += (w0.y + w1.y) + (w2.y + w3.y);
            acc.z += (w0.z + w1.z) + (w2.z + w3.z);
            acc.w += (w0.w + w1.w) + (w2.w + w3.w);
        }

        // zero inactive-lane (g==6) contributions, then fold 6 groups -> group 0
        acc.x *= actf; acc.y *= actf; acc.z *= actf; acc.w *= actf;
        acc.x += __shfl(acc.x, lane + 30, 64); acc.y += __shfl(acc.y, lane + 30, 64);
        acc.z += __shfl(acc.z, lane + 30, 64); acc.w += __shfl(acc.w, lane + 30, 64);
        float4 s1, s2;
        s1.x = __shfl(acc.x, lane + 10, 64); s2.x = __shfl(acc.x, lane + 20, 64);
        s1.y = __shfl(acc.y, lane + 10, 64); s2.y = __shfl(acc.y, lane + 20, 64);
        s1.z = __shfl(acc.z, lane + 10, 64); s2.z = __shfl(acc.z, lane + 20, 64);
        s1.w = __shfl(acc.w, lane + 10, 64); s2.w = __shfl(acc.w, lane + 20, 64);
        acc.x += s1.x + s2.x; acc.y += s1.y + s2.y;
        acc.z += s1.z + s2.z; acc.w += s1.w + s2.w;

        const float4 self = t4[(size_t)node * 10 + q];
        const float invv = 1.0f / (float)(d + 1);
        float4 r;
        r.x = (acc.x + self.x) * invv + bq.x;
        r.y = (acc.y + self.y) * invv + bq.y;
        r.z = (acc.z + self.z) * invv + bq.z;
        r.w = (acc.w + self.w) * invv + bq.w;
        if (lane < 10) ((float4*)out)[(size_t)node * 10 + q] = r;
    }
}

extern "C" void kernel_launch(void* const* d_in, const int* in_sizes, int n_in,
                              void* d_out, int out_size, void* d_ws, size_t ws_size,
                              hipStream_t stream) {
    const float* feats = (const float*)d_in[0];
    const int*   src   = (const int*)d_in[1];
    const int*   dst   = (const int*)d_in[2];
    const float* W0    = (const float*)d_in[3];
    const float* b0    = (const float*)d_in[4];
    const float* W1    = (const float*)d_in[5];
    const float* b1    = (const float*)d_in[6];
    const float* W2    = (const float*)d_in[7];
    const float* b2    = (const float*)d_in[8];
    float*       out   = (float*)d_out;

    const int N = in_sizes[0] / N_FEAT;  // 100000
    const int E = in_sizes[1];           // 1600000
    const int PB = (E + 255) / 256;      // bin blocks (6250)
    const int NW = PB * 4;               // bin waves (25000)
    const int BS = (N + 7) / 8;          // nodes per bucket (12500)

    // Workspace (~84 MB). X,Y have one extra 64-float sentinel row.
    // bins aliases Y's head (bins dead before Y's first write).
    char* p = (char*)d_ws;
    float* X   = (float*)p; p += ((size_t)N * N_FEAT + 64) * sizeof(float);  // 25.6 MB
    float* Y   = (float*)p; p += ((size_t)N * N_FEAT + 64) * sizeof(float);  // 25.6 MB
    unsigned int* bins = (unsigned int*)Y;  // 8*NW*CAPW*4 = 19.2 MB <= 25.6
    int*   deg = (int*)p;   p += ((size_t)N << 4) * sizeof(int);       // padded deg, 6.4 MB
    int*   ovf_cnt = (int*)p; p += 4 * sizeof(int);
    int*   ovf = (int*)p;   p += (size_t)OVF_CAP * 2 * sizeof(int);    // 32 KB
    unsigned long long* cnt64 = (unsigned long long*)p;
    p += (size_t)NW * sizeof(unsigned long long);                      // 200 KB
    int*   ell = (int*)p;   p += (size_t)N * CAP * sizeof(int);        // 25.6 MB

    hipMemsetAsync(deg, 0, (((size_t)N << 4) + 4) * sizeof(int), stream);

    constexpr int NPW = 4;
    const int TB = ((N + 7) / 8 + 3) / 4;                 // transform blocks (3125)
    const int IB = 1024;                                  // ell-init blocks
    const int ab = ((N + NPW - 1) / NPW + 3) / 4;         // agg blocks (6250)

    // bin_edges || t0 = feats @ W0^T || ell-sentinel init  (independent)
    prep<<<PB + TB + IB, 256, 0, stream>>>(src, dst, bins, cnt64, ovf, ovf_cnt,
                                           E, BS, NW, feats, W0, X, N, ell, PB, TB, IB);
    fill_from_bins<<<2048, 256, 0, stream>>>(bins, cnt64, ovf, ovf_cnt, deg, ell, NW, BS, N);
    // t1 = relu((seg(t0)+t0)*inv + b0) @ W1^T   (writes Y + Y's sentinel row)
    agg_t_k<64, NPW><<<ab, 256, 0, stream>>>(X, b0, W1, deg, ell, Y, N);
    // t2 = relu((seg(t1)+t1)*inv + b1) @ W2^T   (40-wide; writes X + X40 sentinel row)
    agg_t_k<40, NPW><<<ab, 256, 0, stream>>>(Y, b1, W2, deg, ell, X, N);
    // out = (seg(t2)+t2)*inv + b2
    agg40_k<NPW><<<ab, 256, 0, stream>>>(X, b2, deg, ell, out, N);
}

// Round 5
// 339.296 us; speedup vs baseline: 1.3020x; 1.1316x over previous
//
#include <hip/hip_runtime.h>
#include <hip/hip_bf16.h>

// GraphSAGE (GCN-aggregator) — 3 layers, fp32.
// Structure: transform-then-aggregate ((seg(t)+t)*inv + b, t = h@W^T).
// R12: R11's deg-padding null result falsified the line-contention theory.
// fill's 1.6M device-scope atomicAdds are pinned at ~21 G/s (memory-side
// RMW pipe; WRITE_SIZE ~45B/atomic) regardless of address layout. Fix:
// eliminate global atomics entirely.
//  - bin (in prep): 196 fine buckets (dst>>9), per-256-edge-block slot
//    assignment via LDS atomics; records -> bins[bucket][blk][8] (32B
//    rows), counts -> cnt8[bucket][blk]. No ballot loop, no cnt64.
//  - fill_scan: one block per bucket (196 x 1024 threads); block owns its
//    512 nodes exclusively -> slot counters in LDS, ZERO global atomics;
//    writes dense deg at the end (deg memset dropped).
// Carried: 32-slot ELL planes, sentinel slots (maskless adds), readlane
// h-broadcast epilogue, W in padded LDS.
// fp32 throughout (bf16 would exceed the 7.1e-4 absmax threshold).

#define N_FEAT 64
#define CAP 64      // ELL slots per node (2 planes of 32)
#define CAPB 8      // bin slots per (bucket, edge-block); 32B row
#define BSH 9       // bucket shift: 512 nodes per bucket
#define BSZ 512
#define OVF_CAP 4096

__device__ __forceinline__ float rl(float v, int l) {
    return __int_as_float(__builtin_amdgcn_readlane(__float_as_int(v), l));
}

// ---- bin body: LDS-counter binning into 196 fine buckets ----
__device__ __forceinline__ void bin_body(const int* __restrict__ src,
                                         const int* __restrict__ dst,
                                         unsigned int* __restrict__ bins,   // [NBK,nblk,CAPB]
                                         unsigned char* __restrict__ cnt8,  // [NBK,nblk]
                                         int* __restrict__ ovf, int* __restrict__ ovf_cnt,
                                         int n_edges, int nbk, int nblk, int bid) {
    __shared__ int lcnt[256];  // >= nbk (196)
    const int tid = threadIdx.x;
    lcnt[tid] = 0;
    __syncthreads();

    const int e = bid * 256 + tid;
    const bool valid = e < n_edges;
    int s = 0, d = 0;
    if (valid) { s = src[e]; d = dst[e]; }
    const int b = d >> BSH;
    const unsigned int pack = ((unsigned int)(d & (BSZ - 1)) << 17) | (unsigned int)s;

    if (valid) {
        int slot = atomicAdd(&lcnt[b], 1);  // LDS atomic (CU-local)
        if (slot < CAPB) {
            bins[((size_t)b * nblk + bid) * CAPB + slot] = pack;
        } else {
            int p = atomicAdd(ovf_cnt, 1);  // rare (~tens of edges)
            if (p < OVF_CAP) { ovf[2 * p] = s; ovf[2 * p + 1] = d; }
        }
    }
    __syncthreads();
    if (tid < nbk) {
        int c = lcnt[tid];
        cnt8[(size_t)tid * nblk + bid] = (unsigned char)((c < CAPB) ? c : CAPB);
    }
}

// ---- transform body: t[node][o] = sum_f h[node][f] * W[o][f]  (OUT=64) ----
__device__ __forceinline__ void transform64_body(const float* __restrict__ h,
                                                 const float* __restrict__ W,
                                                 float* __restrict__ t, int n_nodes, int bid) {
    const int lane = threadIdx.x & 63;
    const int wave = (bid << 2) | (threadIdx.x >> 6);
    float4 wreg[16];
    const float4* W4 = (const float4*)(W + lane * N_FEAT);
#pragma unroll
    for (int k = 0; k < 16; ++k) wreg[k] = W4[k];
    const float* wf = (const float*)wreg;

    const int node0 = wave * 8;
    for (int k = 0; k < 8; ++k) {
        const int node = node0 + k;
        if (node >= n_nodes) return;  // wave-uniform
        const float hv = h[(size_t)node * N_FEAT + lane];
        float acc = 0.f;
#pragma unroll
        for (int f = 0; f < 64; ++f) acc = fmaf(rl(hv, f), wf[f], acc);
        t[(size_t)node * N_FEAT + lane] = acc;
    }
}

// ---- ell sentinel init + X zero-row ----
__device__ __forceinline__ void ell_init_body(int* __restrict__ ell,
                                              float* __restrict__ xz,
                                              int n_nodes, int bid, int nb) {
    const size_t total4 = (size_t)n_nodes * (CAP / 4);
    int4* e4 = (int4*)ell;
    const int4 sv = make_int4(n_nodes, n_nodes, n_nodes, n_nodes);
    for (size_t i = (size_t)bid * 256 + threadIdx.x; i < total4; i += (size_t)nb * 256)
        e4[i] = sv;
    if (bid == 0 && threadIdx.x < 64) xz[threadIdx.x] = 0.f;  // sentinel row of t0
}

// ---- fused: bin_edges || transform0 || ell-init (block-range split) ----
__global__ __launch_bounds__(256) void prep(const int* __restrict__ src,
                                            const int* __restrict__ dst,
                                            unsigned int* __restrict__ bins,
                                            unsigned char* __restrict__ cnt8,
                                            int* __restrict__ ovf, int* __restrict__ ovf_cnt,
                                            int n_edges, int nbk, int nblk,
                                            const float* __restrict__ feats,
                                            const float* __restrict__ W0,
                                            float* __restrict__ t0, int n_nodes,
                                            int* __restrict__ ell,
                                            int PB, int TB, int IB) {
    const int b = (int)blockIdx.x;
    if (b < PB)
        bin_body(src, dst, bins, cnt8, ovf, ovf_cnt, n_edges, nbk, nblk, b);
    else if (b < PB + TB)
        transform64_body(feats, W0, t0, n_nodes, b - PB);
    else
        ell_init_body(ell, t0 + (size_t)n_nodes * N_FEAT, n_nodes, b - PB - TB, IB);
}

// ---- phase 2: atomic-free fill. Block b owns bucket b (512 nodes);
// slot counters in LDS; scans the bucket's bins rows; writes dense deg. ----
__global__ __launch_bounds__(1024) void fill_scan(const unsigned int* __restrict__ bins,
                                                  const unsigned char* __restrict__ cnt8,
                                                  const int* __restrict__ ovf,
                                                  const int* __restrict__ ovf_cnt,
                                                  int* __restrict__ deg,
                                                  int* __restrict__ ell,
                                                  int nblk, int n_nodes) {
    __shared__ int lcnt[BSZ];
    const int tid = threadIdx.x;
    const int b = (int)blockIdx.x;
    if (tid < BSZ) lcnt[tid] = 0;
    __syncthreads();

    const int base_node = b << BSH;
    const int4* b4 = (const int4*)bins;  // 2 int4 per row (CAPB=8, 32B aligned)
    const unsigned char* cb = cnt8 + (size_t)b * nblk;

    for (int seg = tid; seg < nblk; seg += 1024) {
        const int n = cb[seg];
        if (n == 0) continue;
        const size_t ro = ((size_t)b * nblk + seg) * 2;
        int4 r0 = b4[ro];
        int4 r1 = (n > 4) ? b4[ro + 1] : make_int4(0, 0, 0, 0);
        unsigned int rec[8] = {(unsigned)r0.x, (unsigned)r0.y, (unsigned)r0.z, (unsigned)r0.w,
                               (unsigned)r1.x, (unsigned)r1.y, (unsigned)r1.z, (unsigned)r1.w};
#pragma unroll
        for (int r = 0; r < CAPB; ++r) {
            if (r < n) {
                const unsigned int v = rec[r];
                const int ld = (int)(v >> 17);
                const int sv = (int)(v & 0x1FFFFu);
                const int slot = atomicAdd(&lcnt[ld], 1);  // LDS atomic
                if (slot < CAP) {
                    const int dn = base_node + ld;
                    ell[(((size_t)(slot >> 5) * n_nodes + dn) << 5) + (slot & 31)] = sv;
                }
            }
        }
    }

    // overflow drain (expected ~tens of entries)
    int oc = *ovf_cnt;
    oc = (oc < OVF_CAP) ? oc : OVF_CAP;
    for (int i = tid; i < oc; i += 1024) {
        const int sv = ovf[2 * i], d = ovf[2 * i + 1];
        if ((d >> BSH) == b) {
            const int slot = atomicAdd(&lcnt[d - base_node], 1);
            if (slot < CAP)
                ell[(((size_t)(slot >> 5) * n_nodes + d) << 5) + (slot & 31)] = sv;
        }
    }
    __syncthreads();
    if (tid < BSZ) {
        const int node = base_node + tid;
        if (node < n_nodes) deg[node] = lcnt[tid];
    }
}

// ---- fused agg + next transform:
//   h = relu((seg(t)+t)*inv + b); t_next[node][o] = sum_f h[f]*Wn[o][f]
// 32-slot ELL planes; sentinel slots hold index N (zero row) -> maskless adds.
// Epilogue: h broadcast via readlane; W rows from padded LDS.
template <int OUTW, int NPW>
__global__ __launch_bounds__(256, 4) void agg_t_k(const float* __restrict__ t,
                                                  const float* __restrict__ bias,  // [64]
                                                  const float* __restrict__ Wn,    // [OUTW,64]
                                                  const int* __restrict__ deg,     // [N] dense
                                                  const int* __restrict__ ell,
                                                  float* __restrict__ tn,          // [N,OUTW]
                                                  int n_nodes) {
    __shared__ float4 sW[64 * 17];  // rows padded +1 float4 (structural-min banks)
    if (blockIdx.x == 0 && threadIdx.x < OUTW)
        tn[(size_t)n_nodes * OUTW + threadIdx.x] = 0.f;  // sentinel row for next layer
    {
        const float4* Wg = (const float4*)Wn;
        for (int i = threadIdx.x; i < OUTW * 16; i += 256)
            sW[(i >> 4) * 17 + (i & 15)] = Wg[i];
    }
    __syncthreads();

    const int lane = threadIdx.x & 63;
    const int w = threadIdx.x >> 6;
    const int wave = (blockIdx.x << 2) | w;
    const int g = lane >> 4;
    const int q = lane & 15;
    const float4* t4 = (const float4*)t;
    const float4* tq = t4 + q;
    const int4* ell4 = (const int4*)ell;
    const float4 bq = ((const float4*)bias)[q];
    const int wrow = (OUTW == 64) ? lane : ((lane < OUTW) ? lane : 0);
    const float4* wrow4 = sW + wrow * 17;
    const bool has_out = (OUTW == 64) || (lane < OUTW);

    const int node0 = wave * NPW;
    if (node0 >= n_nodes) return;
    const int gi = g * 2;  // int4 pair base within a node's 8 int4 idx words

#define GATH8(V, I)                         \
    do {                                    \
        V[0] = tq[(size_t)(I)[0].x * 16];   \
        V[1] = tq[(size_t)(I)[0].y * 16];   \
        V[2] = tq[(size_t)(I)[0].z * 16];   \
        V[3] = tq[(size_t)(I)[0].w * 16];   \
        V[4] = tq[(size_t)(I)[1].x * 16];   \
        V[5] = tq[(size_t)(I)[1].y * 16];   \
        V[6] = tq[(size_t)(I)[1].z * 16];   \
        V[7] = tq[(size_t)(I)[1].w * 16];   \
    } while (0)

#define EPILOGUE_GEMM(R)                                  \
    float o0 = 0.f, o1 = 0.f;                             \
    _Pragma("unroll")                                     \
    for (int c = 0; c < 16; c += 2) {                     \
        float4 w0 = wrow4[c];                             \
        float4 w1 = wrow4[c + 1];                         \
        o0 = fmaf(rl((R).x, c), w0.x, o0);                \
        o0 = fmaf(rl((R).y, c), w0.y, o0);                \
        o0 = fmaf(rl((R).z, c), w0.z, o0);                \
        o0 = fmaf(rl((R).w, c), w0.w, o0);                \
        o1 = fmaf(rl((R).x, c + 1), w1.x, o1);            \
        o1 = fmaf(rl((R).y, c + 1), w1.y, o1);            \
        o1 = fmaf(rl((R).z, c + 1), w1.z, o1);            \
        o1 = fmaf(rl((R).w, c + 1), w1.w, o1);            \
    }

    if (node0 + NPW <= n_nodes) {
        int dgv[NPW];
#pragma unroll
        for (int k = 0; k < NPW; ++k) dgv[k] = deg[node0 + k];

        int4 ix[2][2];
        float4 vb[2][8];
        float4 selfb[2];
        ix[0][0] = ell4[(size_t)node0 * 8 + gi];
        ix[0][1] = ell4[(size_t)node0 * 8 + gi + 1];
        if (NPW > 1) {
            ix[1][0] = ell4[(size_t)(node0 + 1) * 8 + gi];
            ix[1][1] = ell4[(size_t)(node0 + 1) * 8 + gi + 1];
        }
        selfb[0] = t4[(size_t)node0 * 16 + q];
        GATH8(vb[0], ix[0]);

#pragma unroll
        for (int k = 0; k < NPW; ++k) {
            if (k + 1 < NPW) {  // issue next node's self + 8 gathers
                selfb[(k + 1) & 1] = t4[(size_t)(node0 + k + 1) * 16 + q];
                GATH8(vb[(k + 1) & 1], ix[(k + 1) & 1]);
            }
            if (k + 2 < NPW) {  // refill idx two ahead
                ix[k & 1][0] = ell4[(size_t)(node0 + k + 2) * 8 + gi];
                ix[k & 1][1] = ell4[(size_t)(node0 + k + 2) * 8 + gi + 1];
            }
            const int node = node0 + k;
            const int d = dgv[k];
            const float4* v = vb[k & 1];
            float4 acc;
            acc.x = ((v[0].x + v[1].x) + (v[2].x + v[3].x)) +
                    ((v[4].x + v[5].x) + (v[6].x + v[7].x));
            acc.y = ((v[0].y + v[1].y) + (v[2].y + v[3].y)) +
                    ((v[4].y + v[5].y) + (v[6].y + v[7].y));
            acc.z = ((v[0].z + v[1].z) + (v[2].z + v[3].z)) +
                    ((v[4].z + v[5].z) + (v[6].z + v[7].z));
            acc.w = ((v[0].w + v[1].w) + (v[2].w + v[3].w)) +
                    ((v[4].w + v[5].w) + (v[6].w + v[7].w));

            if (d > 32) {  // plane 1 (rare: P(deg>32) ~ 1e-4)
                int4 j0 = ell4[((size_t)(n_nodes + node)) * 8 + gi];
                int4 j1 = ell4[((size_t)(n_nodes + node)) * 8 + gi + 1];
                {
                    float4 u0 = tq[(size_t)j0.x * 16];
                    float4 u1 = tq[(size_t)j0.y * 16];
                    float4 u2 = tq[(size_t)j0.z * 16];
                    float4 u3 = tq[(size_t)j0.w * 16];
                    acc.x += (u0.x + u1.x) + (u2.x + u3.x);
                    acc.y += (u0.y + u1.y) + (u2.y + u3.y);
                    acc.z += (u0.z + u1.z) + (u2.z + u3.z);
                    acc.w += (u0.w + u1.w) + (u2.w + u3.w);
                }
                {
                    float4 u0 = tq[(size_t)j1.x * 16];
                    float4 u1 = tq[(size_t)j1.y * 16];
                    float4 u2 = tq[(size_t)j1.z * 16];
                    float4 u3 = tq[(size_t)j1.w * 16];
                    acc.x += (u0.x + u1.x) + (u2.x + u3.x);
                    acc.y += (u0.y + u1.y) + (u2.y + u3.y);
                    acc.z += (u0.z + u1.z) + (u2.z + u3.z);
                    acc.w += (u0.w + u1.w) + (u2.w + u3.w);
                }
            }

            acc.x += __shfl_xor(acc.x, 16, 64); acc.y += __shfl_xor(acc.y, 16, 64);
            acc.z += __shfl_xor(acc.z, 16, 64); acc.w += __shfl_xor(acc.w, 16, 64);
            acc.x += __shfl_xor(acc.x, 32, 64); acc.y += __shfl_xor(acc.y, 32, 64);
            acc.z += __shfl_xor(acc.z, 32, 64); acc.w += __shfl_xor(acc.w, 32, 64);

            // h (relu'd, bias'd) — identical in all 4 groups per lane
            const float invv = 1.0f / (float)(d + 1);
            float4 r;
            r.x = fmaxf((acc.x + selfb[k & 1].x) * invv + bq.x, 0.f);
            r.y = fmaxf((acc.y + selfb[k & 1].y) * invv + bq.y, 0.f);
            r.z = fmaxf((acc.z + selfb[k & 1].z) * invv + bq.z, 0.f);
            r.w = fmaxf((acc.w + selfb[k & 1].w) * invv + bq.w, 0.f);

            // t_next[o] = sum_f h[f] * Wn[o][f]; h[4c+j] = readlane(r[j], c)
            EPILOGUE_GEMM(r);
            if (has_out) tn[(size_t)node * OUTW + lane] = o0 + o1;
        }
    } else {
        // generic tail path (not taken for N=100000, NPW=4)
        for (int k = 0; k < NPW; ++k) {
            const int node = node0 + k;
            if (node >= n_nodes) return;
            const int d = deg[node];
            float4 acc = make_float4(0.f, 0.f, 0.f, 0.f);
            const int np = (d > 32) ? 2 : 1;
            for (int p = 0; p < np; ++p) {
                int4 ii[2];
                ii[0] = ell4[((size_t)p * n_nodes + node) * 8 + gi];
                ii[1] = ell4[((size_t)p * n_nodes + node) * 8 + gi + 1];
                float4 vv[8];
                GATH8(vv, ii);
                acc.x += ((vv[0].x + vv[1].x) + (vv[2].x + vv[3].x)) +
                         ((vv[4].x + vv[5].x) + (vv[6].x + vv[7].x));
                acc.y += ((vv[0].y + vv[1].y) + (vv[2].y + vv[3].y)) +
                         ((vv[4].y + vv[5].y) + (vv[6].y + vv[7].y));
                acc.z += ((vv[0].z + vv[1].z) + (vv[2].z + vv[3].z)) +
                         ((vv[4].z + vv[5].z) + (vv[6].z + vv[7].z));
                acc.w += ((vv[0].w + vv[1].w) + (vv[2].w + vv[3].w)) +
                         ((vv[4].w + vv[5].w) + (vv[6].w + vv[7].w));
            }
            acc.x += __shfl_xor(acc.x, 16, 64); acc.y += __shfl_xor(acc.y, 16, 64);
            acc.z += __shfl_xor(acc.z, 16, 64); acc.w += __shfl_xor(acc.w, 16, 64);
            acc.x += __shfl_xor(acc.x, 32, 64); acc.y += __shfl_xor(acc.y, 32, 64);
            acc.z += __shfl_xor(acc.z, 32, 64); acc.w += __shfl_xor(acc.w, 32, 64);
            float4 self = t4[(size_t)node * 16 + q];
            const float invv = 1.0f / (float)(d + 1);
            float4 r;
            r.x = fmaxf((acc.x + self.x) * invv + bq.x, 0.f);
            r.y = fmaxf((acc.y + self.y) * invv + bq.y, 0.f);
            r.z = fmaxf((acc.z + self.z) * invv + bq.z, 0.f);
            r.w = fmaxf((acc.w + self.w) * invv + bq.w, 0.f);
            EPILOGUE_GEMM(r);
            if (has_out) tn[(size_t)node * OUTW + lane] = o0 + o1;
        }
    }
#undef GATH8
#undef EPILOGUE_GEMM
}

// ---- final: out = (seg(t)+t)*inv + b, 40-wide, 2-deep pipeline ----
template <int NPW>
__global__ __launch_bounds__(256) void agg40_k(const float* __restrict__ t,     // [N,40]
                                               const float* __restrict__ bias,  // [40]
                                               const int* __restrict__ deg,     // [N] dense
                                               const int* __restrict__ ell,
                                               float* __restrict__ out, int n_nodes) {
    const int lane = threadIdx.x & 63;
    const int wave = (blockIdx.x << 2) | (threadIdx.x >> 6);
    const int g = lane / 10;      // 0..5 active, 6 idle
    const int q = lane - g * 10;  // 0..9
    const bool act = lane < 60;
    const float actf = act ? 1.f : 0.f;
    const float4* t4 = (const float4*)t;
    const float4 bq = ((const float4*)bias)[q];
    const int node0 = wave * NPW;
    if (node0 >= n_nodes) return;

    int nmax = NPW;
    if (node0 + NPW > n_nodes) nmax = n_nodes - node0;

    int dg[NPW];
#pragma unroll
    for (int k = 0; k < NPW; ++k) dg[k] = deg[node0 + ((k < nmax) ? k : 0)];

    auto eaddr = [&](int nd, int e) -> size_t {
        return (((size_t)(e >> 5) * n_nodes + nd) << 5) + (e & 31);
    };

    float4 vb[2][4];
    auto issue = [&](int slot, int k) {
        const int node = node0 + k;
        int i0 = ell[eaddr(node, g + 0)];    // sentinel slots -> zero row
        int i1 = ell[eaddr(node, g + 6)];
        int i2 = ell[eaddr(node, g + 12)];
        int i3 = ell[eaddr(node, g + 18)];
        vb[slot][0] = t4[(size_t)i0 * 10 + q];
        vb[slot][1] = t4[(size_t)i1 * 10 + q];
        vb[slot][2] = t4[(size_t)i2 * 10 + q];
        vb[slot][3] = t4[(size_t)i3 * 10 + q];
    };

    issue(0, 0);
#pragma unroll
    for (int k = 0; k < NPW; ++k) {
        if (k + 1 < NPW) issue((k + 1) & 1, k + 1);
        if (k >= nmax) break;
        const int node = node0 + k;
        const int d = dg[k];
        const float4* v = vb[k & 1];
        float4 acc;
        acc.x = (v[0].x + v[1].x) + (v[2].x + v[3].x);
        acc.y = (v[0].y + v[1].y) + (v[2].y + v[3].y);
        acc.z = (v[0].z + v[1].z) + (v[2].z + v[3].z);
        acc.w = (v[0].w + v[1].w) + (v[2].w + v[3].w);

        const int dcap = (d < CAP) ? d : CAP;
        for (int u = 1; u * 24 < dcap; ++u) {  // tail (deg > 24); keep CAP clamps
            const int eb = u * 24 + g;
            const bool k0 = act && (eb + 0 < d) && (eb + 0 < CAP);
            const bool k1 = act && (eb + 6 < d) && (eb + 6 < CAP);
            const bool k2 = act && (eb + 12 < d) && (eb + 12 < CAP);
            const bool k3 = act && (eb + 18 < d) && (eb + 18 < CAP);
            int i0 = k0 ? ell[eaddr(node, eb + 0)] : n_nodes;
            int i1 = k1 ? ell[eaddr(node, eb + 6)] : n_nodes;
            int i2 = k2 ? ell[eaddr(node, eb + 12)] : n_nodes;
            int i3 = k3 ? ell[eaddr(node, eb + 18)] : n_nodes;
            float4 w0 = t4[(size_t)i0 * 10 + q];
            float4 w1 = t4[(size_t)i1 * 10 + q];
            float4 w2 = t4[(size_t)i2 * 10 + q];
            float4 w3 = t4[(size_t)i3 * 10 + q];
            acc.x += (w0.x + w1.x) + (w2.x + w3.x);
            acc.y += (w0.y + w1.y) + (w2.y + w3.y);
            acc.z += (w0.z + w1.z) + (w2.z + w3.z);
            acc.w += (w0.w + w1.w) + (w2.w + w3.w);
        }

        // zero inactive-lane (g==6) contributions, then fold 6 groups -> group 0
        acc.x *= actf; acc.y *= actf; acc.z *= actf; acc.w *= actf;
        acc.x += __shfl(acc.x, lane + 30, 64); acc.y += __shfl(acc.y, lane + 30, 64);
        acc.z += __shfl(acc.z, lane + 30, 64); acc.w += __shfl(acc.w, lane + 30, 64);
        float4 s1, s2;
        s1.x = __shfl(acc.x, lane + 10, 64); s2.x = __shfl(acc.x, lane + 20, 64);
        s1.y = __shfl(acc.y, lane + 10, 64); s2.y = __shfl(acc.y, lane + 20, 64);
        s1.z = __shfl(acc.z, lane + 10, 64); s2.z = __shfl(acc.z, lane + 20, 64);
        s1.w = __shfl(acc.w, lane + 10, 64); s2.w = __shfl(acc.w, lane + 20, 64);
        acc.x += s1.x + s2.x; acc.y += s1.y + s2.y;
        acc.z += s1.z + s2.z; acc.w += s1.w + s2.w;

        const float4 self = t4[(size_t)node * 10 + q];
        const float invv = 1.0f / (float)(d + 1);
        float4 r;
        r.x = (acc.x + self.x) * invv + bq.x;
        r.y = (acc.y + self.y) * invv + bq.y;
        r.z = (acc.z + self.z) * invv + bq.z;
        r.w = (acc.w + self.w) * invv + bq.w;
        if (lane < 10) ((float4*)out)[(size_t)node * 10 + q] = r;
    }
}

extern "C" void kernel_launch(void* const* d_in, const int* in_sizes, int n_in,
                              void* d_out, int out_size, void* d_ws, size_t ws_size,
                              hipStream_t stream) {
    const float* feats = (const float*)d_in[0];
    const int*   src   = (const int*)d_in[1];
    const int*   dst   = (const int*)d_in[2];
    const float* W0    = (const float*)d_in[3];
    const float* b0    = (const float*)d_in[4];
    const float* W1    = (const float*)d_in[5];
    const float* b1    = (const float*)d_in[6];
    const float* W2    = (const float*)d_in[7];
    const float* b2    = (const float*)d_in[8];
    float*       out   = (float*)d_out;

    const int N = in_sizes[0] / N_FEAT;  // 100000
    const int E = in_sizes[1];           // 1600000
    const int NBLK = (E + 255) / 256;    // edge blocks (6250)
    const int NBK = (N + BSZ - 1) >> BSH;  // fine buckets (196)

    // Workspace (~93 MB). X,Y have one extra 64-float sentinel row.
    // bins (39.2 MB) aliases Y (25.6 MB) + explicit pad (bins dead before
    // Y's first write in agg layer 1; regions after the pad are live in fill).
    char* p = (char*)d_ws;
    const size_t xb = ((size_t)N * N_FEAT + 64) * sizeof(float);  // 25.6 MB
    float* X = (float*)p; p += xb;
    float* Y = (float*)p; p += xb;
    unsigned int* bins = (unsigned int*)Y;
    const size_t binsb = (size_t)NBK * NBLK * CAPB * sizeof(unsigned int);  // 39.2 MB
    if (binsb > xb) p += binsb - xb;                                // pad past Y
    int* deg = (int*)p;     p += (size_t)N * sizeof(int);           // 400 KB (dense)
    int* ovf_cnt = (int*)p; p += 16;
    int* ovf = (int*)p;     p += (size_t)OVF_CAP * 2 * sizeof(int); // 32 KB
    unsigned char* cnt8 = (unsigned char*)p;
    p += ((size_t)NBK * NBLK + 15) & ~(size_t)15;                   // 1.23 MB
    int* ell = (int*)p;     p += (size_t)N * CAP * sizeof(int);     // 25.6 MB

    hipMemsetAsync(ovf_cnt, 0, sizeof(int), stream);  // deg memset dropped: fill writes all

    constexpr int NPW = 4;
    const int PB = NBLK;                                  // bin blocks (6250)
    const int TB = ((N + 7) / 8 + 3) / 4;                 // transform blocks (3125)
    const int IB = 1024;                                  // ell-init blocks
    const int ab = ((N + NPW - 1) / NPW + 3) / 4;         // agg blocks (6250)

    // bin_edges || t0 = feats @ W0^T || ell-sentinel init  (independent)
    prep<<<PB + TB + IB, 256, 0, stream>>>(src, dst, bins, cnt8, ovf, ovf_cnt,
                                           E, NBK, NBLK, feats, W0, X, N, ell, PB, TB, IB);
    // atomic-free scatter: one block per bucket, LDS slot counters
    fill_scan<<<NBK, 1024, 0, stream>>>(bins, cnt8, ovf, ovf_cnt, deg, ell, NBLK, N);
    // t1 = relu((seg(t0)+t0)*inv + b0) @ W1^T   (writes Y + Y's sentinel row)
    agg_t_k<64, NPW><<<ab, 256, 0, stream>>>(X, b0, W1, deg, ell, Y, N);
    // t2 = relu((seg(t1)+t1)*inv + b1) @ W2^T   (40-wide; writes X + X40 sentinel row)
    agg_t_k<40, NPW><<<ab, 256, 0, stream>>>(Y, b1, W2, deg, ell, X, N);
    // out = (seg(t2)+t2)*inv + b2
    agg40_k<NPW><<<ab, 256, 0, stream>>>(X, b2, deg, ell, out, N);
}